// Round 1
// 476.235 us; speedup vs baseline: 1.2527x; 1.2527x over previous
//
#include <hip/hip_runtime.h>
#include <hip/hip_bf16.h>
#include <hip/hip_fp8.h>
#include <math.h>

// Problem constants: b=4, c=64, h=w=256, WS=8, SHIFT=4, HEADS=4, d=16, hidden=256
// Windows: 32x32 per image * 4 images = 4096; 64 tokens/window.
//
// Workspace layout (peak 160 MB):
//   Cb  bf16 32MB [0,32M)    x3 token-major        written k2, read k3+k5
//   A   bf16 32MB [32,64M)   shortcut token-major  written k1, read k2 (dead after)
//   Bw  bf16 32MB [64,96M)   shifted windows       written k1, read k2 (dead after)
//   D   fp8  64MB [32,96M)   hid image layout      written k3 (aliases A+Bw), read k4
//   E   fp8  64MB [96,160M)  hid+conv image layout written k4, read k5
//   Wbf bf16 ~66KB at [96M, 96M+66K): prep-converted qkvw/projw/rpb/fc1w,
//       read by k2/k3, then overwritten by k4's E write (safe: stream order).
//   fc2w_bf at [32M): written by k_cvt AFTER k4 (D dead), read k5.

typedef __bf16  bf16x8  __attribute__((ext_vector_type(8)));
typedef float   f32x4   __attribute__((ext_vector_type(4)));
typedef unsigned short ushortx8 __attribute__((ext_vector_type(8)));

__device__ __forceinline__ float gelu_f(float v) {
    // tanh-form gelu: 0.5v(1+tanh(0.79788456(v+0.044715v^3))) = v - v/(e^u+1)
    // with u = 1.5957691216 v + 0.0713548354 v^3. |err| <~2e-3, << fp8 step.
    float u = v * fmaf(0.0713548354f, v * v, 1.5957691216f);
    float t = __expf(u);                        // t=inf -> rcp=0 -> v;  t=0 -> v-v=0
    float r = __builtin_amdgcn_rcpf(t + 1.0f);
    return v - v * r;
}
__device__ __forceinline__ unsigned char f32_to_fp8(float v) {
    __hip_fp8_e4m3 t(v);
    return (unsigned char)t.__x;
}
__device__ __forceinline__ float fp8_to_f32(unsigned char u) {
    __hip_fp8_e4m3 t;
    t.__x = (__hip_fp8_storage_t)u;
    return (float)t;
}
__device__ __forceinline__ unsigned short f2bf(float f) {   // RNE, matches HW
    unsigned int u = __builtin_bit_cast(unsigned int, f);
    u += 0x7fffu + ((u >> 16) & 1u);
    return (unsigned short)(u >> 16);
}
__device__ __forceinline__ float bf2f(unsigned short u) {
    return __builtin_bit_cast(float, ((unsigned int)u) << 16);
}

// ---------------------------------------------------------------------------
// Kernel 0: one-time weight conversion to bf16 (amortizes 4096 blocks' worth
// of per-block fp32 loads + f2bf conversions in k2/k3).
// ---------------------------------------------------------------------------
__global__ __launch_bounds__(256) void k_prep(
        const float* __restrict__ qkvw, const float* __restrict__ projw,
        const float* __restrict__ rpb,  const float* __restrict__ fc1w,
        unsigned short* __restrict__ qkvw_bf, unsigned short* __restrict__ projw_bf,
        unsigned short* __restrict__ rpb_bf,  unsigned short* __restrict__ fc1w_bf) {
    const int i = blockIdx.x * 256 + threadIdx.x;   // grid 64*256 = 16384
    if (i < 12288) qkvw_bf[i] = f2bf(qkvw[i]);
    if (i < 4096)  projw_bf[i] = f2bf(projw[i]);
    if (i < 900)   rpb_bf[i]   = f2bf(rpb[i]);
    if (i < 16384) fc1w_bf[i]  = f2bf(fc1w[i]);
}

__global__ __launch_bounds__(256) void k_cvt(const float* __restrict__ src,
        unsigned short* __restrict__ dst, int n) {
    const int i = blockIdx.x * 256 + threadIdx.x;
    if (i < n) dst[i] = f2bf(src[i]);
}

// ---------------------------------------------------------------------------
// Kernel 1: LN1 + transpose. Reads x (b,c,h,w). Writes:
//   A  : shortcut, token-major bf16 [b*65536 tokens][64 ch]
//   Bw : normalized, shifted+window-partitioned bf16 [4096 win][64 tok][64 ch]
// ---------------------------------------------------------------------------
__global__ __launch_bounds__(256) void k_ln1(const float* __restrict__ x,
        const float* __restrict__ w1, const float* __restrict__ b1,
        unsigned short* __restrict__ A, unsigned short* __restrict__ Bw) {
    __shared__ float tile[64 * 65];           // [ch][token]
    __shared__ float red0[256], red1[256];
    __shared__ float muv[64], rsv[64], lw[64], lb[64];
    const int tid = threadIdx.x;
    const int gid = blockIdx.x;
    const int xc = gid & 3, y = (gid >> 2) & 255, b = gid >> 10;
    const int x0 = xc * 64;
    if (tid < 64) { lw[tid] = w1[tid]; lb[tid] = b1[tid]; }

    const float* xb = x + ((size_t)b * 64) * 65536 + y * 256 + x0;
    {
        const int tk = tid & 63, cl = tid >> 6;
        for (int it = 0; it < 16; ++it) {
            int cc = cl + 4 * it;
            tile[cc * 65 + tk] = xb[(size_t)cc * 65536 + tk];   // coalesced
        }
    }
    __syncthreads();
    {
        const int tk = tid & 63, cl = tid >> 6;
        float s = 0.f, s2 = 0.f;
        #pragma unroll
        for (int k = 0; k < 16; ++k) {
            float v = tile[(cl * 16 + k) * 65 + tk];
            s += v; s2 += v * v;
        }
        red0[cl * 64 + tk] = s; red1[cl * 64 + tk] = s2;
    }
    __syncthreads();
    if (tid < 64) {
        float s  = red0[tid] + red0[64 + tid] + red0[128 + tid] + red0[192 + tid];
        float s2 = red1[tid] + red1[64 + tid] + red1[128 + tid] + red1[192 + tid];
        float mu = s * (1.f / 64.f);
        float var = s2 * (1.f / 64.f) - mu * mu;
        muv[tid] = mu; rsv[tid] = rsqrtf(var + 1e-5f);
    }
    __syncthreads();
    const int ch = tid & 63, tl = tid >> 6;
    const int ys = (y + 252) & 255;          // shifted row (roll -4)
    const int wy = ys >> 3, py = ys & 7;
    for (int it = 0; it < 16; ++it) {
        int t = tl + 4 * it;
        float v = tile[ch * 65 + t];         // stride 65 -> free 2-way
        int tok = (b << 16) + y * 256 + x0 + t;
        A[(size_t)tok * 64 + ch] = f2bf(v);
        float vn = (v - muv[t]) * rsv[t] * lw[ch] + lb[ch];
        int xs = (x0 + t + 252) & 255;
        int wx = xs >> 3, px = xs & 7;
        int widx = (b << 10) + (wy << 5) + wx;
        int pos = (py << 3) + px;
        Bw[((size_t)widx * 64 + pos) * 64 + ch] = f2bf(vn);
    }
}

// ---------------------------------------------------------------------------
// Kernel 2: windowed attention, MFMA bf16 — restructured:
//  * bf16 weights from prep kernel (no per-block f32 loads / conversions)
//  * single-pass W staging with b128 copies; 5 barriers (was 9)
//  * LDS reuse: Ws holds qkvw -> then Q[0,4K) K[4K,8K) V[8K,12.8K)
//               -> after S-MFMA barrier: P over Q (XOR-swizzled [tok][64]),
//                  projw over K (XOR-swizzled [oc][64])
//  * interior windows (94%) skip the shift-mask entirely (uniform branch)
//  * rpb index hoisted: idx = rbA[r] + h - offj4[nt]
//  * softmax stores UNNORMALIZED P; 1/sum applied to 16 PV outputs instead
// ---------------------------------------------------------------------------
__global__ __launch_bounds__(256) void k_attn(
        const unsigned short* __restrict__ Bw,
        const unsigned short* __restrict__ qkvw_bf,
        const unsigned short* __restrict__ projw_bf,
        const unsigned short* __restrict__ rpb_bf,
        const float* __restrict__ qkvb,
        const float* __restrict__ projb,
        const unsigned short* __restrict__ A, unsigned short* __restrict__ Cb) {
    __shared__ __align__(16) unsigned short Xs[4608];    // [64][72] X; later o
    __shared__ __align__(16) unsigned short Ws[13824];   // [192][72] W; then QKV/P/projw
    __shared__ __align__(8)  unsigned short rpbl[900];
    __shared__ float qkvbl[192];
    __shared__ float projbl[64];

    const int tid = threadIdx.x;
    const int lane = tid & 63, wv = tid >> 6;
    const int l15 = lane & 15, quad = lane >> 4;
    const int widx = blockIdx.x;
    const int wib = widx & 1023;
    const int wy = wib >> 5, wx = wib & 31, bimg = widx >> 10;
    const bool edge = (wy == 31) | (wx == 31);   // only these windows have a mask

    const f32x4 zz = {0.f, 0.f, 0.f, 0.f};
    const ushortx8 zu = {0, 0, 0, 0, 0, 0, 0, 0};
    const bf16x8 z8 = __builtin_bit_cast(bf16x8, zu);

    // prefetch projw (2 granules/thread) — consumed after the post-S barrier
    const ushortx8 pw0 = *(const ushortx8*)(projw_bf + tid * 8);
    const ushortx8 pw1 = *(const ushortx8*)(projw_bf + (256 + tid) * 8);

    // stage X: each wave stages its OWN 16 token rows (wave-private)
    {
        const unsigned short* Xg = Bw + (size_t)widx * 4096 + wv * 1024;
        #pragma unroll
        for (int it = 0; it < 2; ++it) {
            int g = it * 64 + lane;                 // granule 0..127
            int row = g >> 3, c8 = g & 7;
            *(ushortx8*)&Xs[(wv * 16 + row) * 72 + c8 * 8] =
                *(const ushortx8*)(Xg + g * 8);
        }
    }
    // stage full qkvw (192 rows, cooperative, b128)
    #pragma unroll
    for (int it = 0; it < 6; ++it) {
        int g = it * 256 + tid;                     // granule 0..1535
        int row = g >> 3, c8 = g & 7;
        *(ushortx8*)&Ws[row * 72 + c8 * 8] = *(const ushortx8*)(qkvw_bf + g * 8);
    }
    if (tid < 225) *(uint2*)&rpbl[tid * 4] = *(const uint2*)(rpb_bf + tid * 4);
    if (tid < 192) qkvbl[tid] = qkvb[tid];
    if (tid < 64)  projbl[tid] = projb[tid];
    __syncthreads();                                // B1

    // QKV: 24 MFMA/thread (A = own 16 token rows of X, B = all 192 W rows)
    f32x4 qacc[12];
    #pragma unroll
    for (int i = 0; i < 12; ++i) qacc[i] = zz;
    {
        const bf16x8 av0 = *(const bf16x8*)&Xs[(16 * wv + l15) * 72 + quad * 8];
        const bf16x8 av1 = *(const bf16x8*)&Xs[(16 * wv + l15) * 72 + 32 + quad * 8];
        #pragma unroll
        for (int gl = 0; gl < 12; ++gl) {
            bf16x8 bv0 = *(const bf16x8*)&Ws[(gl * 16 + l15) * 72 + quad * 8];
            qacc[gl] = __builtin_amdgcn_mfma_f32_16x16x32_bf16(av0, bv0, qacc[gl], 0, 0, 0);
            bf16x8 bv1 = *(const bf16x8*)&Ws[(gl * 16 + l15) * 72 + 32 + quad * 8];
            qacc[gl] = __builtin_amdgcn_mfma_f32_16x16x32_bf16(av1, bv1, qacc[gl], 0, 0, 0);
        }
    }
    __syncthreads();                                // B2 (all W reads done)

    // write Q (scaled) / K / V into Ws
    #pragma unroll
    for (int g = 0; g < 12; ++g) {
        #pragma unroll
        for (int r = 0; r < 4; ++r) {
            int tok = 16 * wv + quad * 4 + r;
            int oc  = g * 16 + l15;
            float v = qacc[g][r] + qkvbl[oc];
            if (g < 4)       Ws[g * 1024 + tok * 16 + l15] = f2bf(v * 0.25f);
            else if (g < 8)  Ws[4096 + (g - 4) * 1024 + tok * 16 + l15] = f2bf(v);
            else             Ws[8192 + ((g - 8) * 16 + l15) * 72 + tok] = f2bf(v);
        }
    }
    __syncthreads();                                // B3

    // S = Q K^T  (16 MFMA/thread)
    f32x4 sacc[4][4];
    #pragma unroll
    for (int h = 0; h < 4; ++h) {
        bf16x8 qa = z8;
        if (quad < 2) qa = *(const bf16x8*)&Ws[h * 1024 + (16 * wv + l15) * 16 + quad * 8];
        #pragma unroll
        for (int nt = 0; nt < 4; ++nt) {
            bf16x8 kf = z8;
            if (quad < 2) kf = *(const bf16x8*)&Ws[4096 + h * 1024 + (nt * 16 + l15) * 16 + quad * 8];
            sacc[h][nt] = __builtin_amdgcn_mfma_f32_16x16x32_bf16(qa, kf, zz, 0, 0, 0);
        }
    }
    __syncthreads();                                // B4 (Q/K reads done)

    // stage projw into the dead K region, XOR-swizzled [oc][64]
    {
        const int r0 = tid >> 3;
        Ws[4096 + r0 * 64 + (((tid & 7) ^ (r0 & 7)) << 3)] = 0;   // placeholder to keep types
        *(ushortx8*)&Ws[4096 + r0 * 64 + (((tid & 7) ^ (r0 & 7)) << 3)] = pw0;
        const int g1 = 256 + tid, r1 = g1 >> 3;
        *(ushortx8*)&Ws[4096 + r1 * 64 + (((g1 & 7) ^ (r1 & 7)) << 3)] = pw1;
    }

    // per-thread j constants
    const int jhi = l15 >> 3, jlo = l15 & 7;
    int offj4[4], regj[4];
    #pragma unroll
    for (int nt = 0; nt < 4; ++nt) {
        int j = nt * 16 + l15;
        int jy = j >> 3, jx = j & 7;
        offj4[nt] = (jy * 15 + jx) * 4;
        regj[nt] = 0;
        if (edge) {
            int ysj = wy * 8 + jy, xsj = wx * 8 + jx;
            regj[nt] = (ysj >= 252 ? 2 : (ysj >= 248 ? 1 : 0)) * 3
                     + (xsj >= 252 ? 2 : (xsj >= 248 ? 1 : 0));
        }
    }
    // per-r constants
    int rbA[4], regiA[4], pbaseA[4], i7A[4];
    #pragma unroll
    for (int r = 0; r < 4; ++r) {
        const int i = 16 * wv + quad * 4 + r;
        const int iy = i >> 3, ix = i & 7;
        rbA[r] = ((iy + 7) * 15 + (ix + 7)) * 4;
        i7A[r] = i & 7;
        pbaseA[r] = i * 64 + jlo;
        regiA[r] = 0;
        if (edge) {
            const int ysi = wy * 8 + iy, xsi = wx * 8 + ix;
            regiA[r] = (ysi >= 252 ? 2 : (ysi >= 248 ? 1 : 0)) * 3
                     + (xsi >= 252 ? 2 : (xsi >= 248 ? 1 : 0));
        }
    }

    // per-head: softmax (P unnormalized into swizzled Q region) + PV
    f32x4 o[4];
    #pragma unroll
    for (int h = 0; h < 4; ++h) {
        float invh[4];
        #pragma unroll
        for (int r = 0; r < 4; ++r) {
            float m0 = -1e30f;
            #pragma unroll
            for (int nt = 0; nt < 4; ++nt) {
                float s = sacc[h][nt][r] + bf2f(rpbl[rbA[r] + h - offj4[nt]]);
                if (edge) s += (regj[nt] == regiA[r]) ? 0.f : -100.f;
                sacc[h][nt][r] = s;
                m0 = fmaxf(m0, s);
            }
            m0 = fmaxf(m0, __shfl_xor(m0, 1));
            m0 = fmaxf(m0, __shfl_xor(m0, 2));
            m0 = fmaxf(m0, __shfl_xor(m0, 4));
            m0 = fmaxf(m0, __shfl_xor(m0, 8));
            float s0 = 0.f;
            #pragma unroll
            for (int nt = 0; nt < 4; ++nt) {
                float e = __expf(sacc[h][nt][r] - m0);
                s0 += e;
                Ws[pbaseA[r] + ((((nt << 1) | jhi) ^ i7A[r]) << 3)] = f2bf(e);
            }
            s0 += __shfl_xor(s0, 1); s0 += __shfl_xor(s0, 2);
            s0 += __shfl_xor(s0, 4); s0 += __shfl_xor(s0, 8);
            invh[r] = 1.f / s0;
        }
        o[h] = zz;
        #pragma unroll
        for (int s = 0; s < 2; ++s) {
            bf16x8 pa = *(const bf16x8*)&Ws[(16 * wv + l15) * 64
                                            + (((s * 4 + quad) ^ (l15 & 7)) << 3)];
            bf16x8 vb = *(const bf16x8*)&Ws[8192 + (h * 16 + l15) * 72 + s * 32 + quad * 8];
            o[h] = __builtin_amdgcn_mfma_f32_16x16x32_bf16(pa, vb, o[h], 0, 0, 0);
        }
        #pragma unroll
        for (int r = 0; r < 4; ++r) o[h][r] *= invh[r];
    }

    // prefetch residual A values (consumed in epilogue; hidden under B5 + proj MFMA)
    unsigned short resid[16];
    #pragma unroll
    for (int r = 0; r < 4; ++r) {
        int tok = 16 * wv + quad * 4 + r;
        int py = tok >> 3, px = tok & 7;
        int yo = (wy * 8 + py + 4) & 255, xo = (wx * 8 + px + 4) & 255;
        size_t gt = ((size_t)bimg << 16) + yo * 256 + xo;
        #pragma unroll
        for (int nt = 0; nt < 4; ++nt)
            resid[r * 4 + nt] = A[gt * 64 + nt * 16 + l15];
    }

    // o -> Xs (own rows only; Xs dead since QKV)
    #pragma unroll
    for (int h = 0; h < 4; ++h)
        #pragma unroll
        for (int r = 0; r < 4; ++r)
            Xs[(16 * wv + quad * 4 + r) * 72 + h * 16 + l15] = f2bf(o[h][r]);
    __syncthreads();                                // B5 (projw + o visible)

    // proj: 8 MFMA/thread
    f32x4 pacc[4];
    #pragma unroll
    for (int nt = 0; nt < 4; ++nt) {
        pacc[nt] = zz;
        #pragma unroll
        for (int s = 0; s < 2; ++s) {
            bf16x8 oa = *(const bf16x8*)&Xs[(16 * wv + l15) * 72 + s * 32 + quad * 8];
            bf16x8 wb = *(const bf16x8*)&Ws[4096 + (nt * 16 + l15) * 64
                                            + (((s * 4 + quad) ^ (l15 & 7)) << 3)];
            pacc[nt] = __builtin_amdgcn_mfma_f32_16x16x32_bf16(oa, wb, pacc[nt], 0, 0, 0);
        }
    }

    // epilogue: bias + residual, un-shift, store Cb
    #pragma unroll
    for (int r = 0; r < 4; ++r) {
        int tok = 16 * wv + quad * 4 + r;
        int py = tok >> 3, px = tok & 7;
        int yo = (wy * 8 + py + 4) & 255, xo = (wx * 8 + px + 4) & 255;
        size_t gt = ((size_t)bimg << 16) + yo * 256 + xo;
        #pragma unroll
        for (int nt = 0; nt < 4; ++nt) {
            int oc = nt * 16 + l15;
            float v = pacc[nt][r] + projbl[oc] + bf2f(resid[r * 4 + nt]);
            Cb[gt * 64 + oc] = f2bf(v);
        }
    }
}

// ---------------------------------------------------------------------------
// Kernel 3: LN2 + fc1 + GELU -> D (image layout fp8), MFMA bf16.
// fc1w staged from prep's bf16 copy (b128, no conversions).
// ---------------------------------------------------------------------------
__global__ __launch_bounds__(256) void k_ln2fc1(const unsigned short* __restrict__ Cb,
        const float* __restrict__ w2, const float* __restrict__ b2,
        const unsigned short* __restrict__ fc1w_bf, const float* __restrict__ fc1b,
        unsigned char* __restrict__ D) {
    __shared__ __align__(16) unsigned short Xb[64 * 72];    // raw->normalized bf16
    __shared__ __align__(16) unsigned short Wb[256 * 72];   // fc1w bf16
    __shared__ float red0[256], red1[256];
    __shared__ float muv[64], rsv[64], lwv[64], lbv[64], fb[256];
    const int tid = threadIdx.x, gid = blockIdx.x;
    const int xc = gid & 3, y = (gid >> 2) & 255, b = gid >> 10;
    const int x0 = xc * 64;
    const int lane = tid & 63, wv = tid >> 6;
    const int l15 = lane & 15, quad = lane >> 4;
    const f32x4 zz = {0.f, 0.f, 0.f, 0.f};

    if (tid < 64) { lwv[tid] = w2[tid]; lbv[tid] = b2[tid]; }
    fb[tid] = fc1b[tid];

    // stage Cb -> Xb (raw bf16, coalesced)
    const unsigned short* Cp = Cb + ((size_t)(b << 16) + y * 256 + x0) * 64;
    #pragma unroll
    for (int it = 0; it < 16; ++it) {
        int tt = wv + 4 * it;
        Xb[tt * 72 + lane] = Cp[tt * 64 + lane];
    }
    // stage fc1w_bf -> Wb (b128 copies)
    {
        const ushortx8* w8 = (const ushortx8*)fc1w_bf;
        #pragma unroll
        for (int it = 0; it < 8; ++it) {
            int idx = it * 256 + tid;               // granule 0..2047
            int row = idx >> 3, c8 = idx & 7;
            *(ushortx8*)&Wb[row * 72 + c8 * 8] = w8[idx];
        }
    }
    __syncthreads();
    // LN stats from bf16 tile
    {
        const int tok = tid & 63, cl = tid >> 6;
        float s = 0.f, s2 = 0.f;
        #pragma unroll
        for (int g = 0; g < 2; ++g) {
            const ushortx8 u = *(const ushortx8*)&Xb[tok * 72 + cl * 16 + g * 8];
            #pragma unroll
            for (int k = 0; k < 8; ++k) { float v = bf2f(u[k]); s += v; s2 += v * v; }
        }
        red0[cl * 64 + tok] = s; red1[cl * 64 + tok] = s2;
    }
    __syncthreads();
    if (tid < 64) {
        float s  = red0[tid] + red0[64 + tid] + red0[128 + tid] + red0[192 + tid];
        float s2 = red1[tid] + red1[64 + tid] + red1[128 + tid] + red1[192 + tid];
        float mu = s * (1.f / 64.f);
        float var = s2 * (1.f / 64.f) - mu * mu;
        muv[tid] = mu; rsv[tid] = rsqrtf(var + 1e-5f);
    }
    __syncthreads();
    // normalize in place
    #pragma unroll
    for (int it = 0; it < 16; ++it) {
        int tt = wv + 4 * it;
        float v = bf2f(Xb[tt * 72 + lane]);
        v = (v - muv[tt]) * rsv[tt] * lwv[lane] + lbv[lane];
        Xb[tt * 72 + lane] = f2bf(v);
    }
    __syncthreads();

    // MFMA: acc[mt][nt], m = 64wv+16mt (hidden ch), n = 16nt (token), K=64
    f32x4 acc[4][4];
    #pragma unroll
    for (int mt = 0; mt < 4; ++mt)
        #pragma unroll
        for (int nt = 0; nt < 4; ++nt) acc[mt][nt] = zz;
    #pragma unroll
    for (int s = 0; s < 2; ++s) {
        bf16x8 Bf[4];
        #pragma unroll
        for (int nt = 0; nt < 4; ++nt)
            Bf[nt] = *(const bf16x8*)&Xb[(nt * 16 + l15) * 72 + s * 32 + quad * 8];
        #pragma unroll
        for (int mt = 0; mt < 4; ++mt) {
            bf16x8 Af = *(const bf16x8*)&Wb[(64 * wv + 16 * mt + l15) * 72 + s * 32 + quad * 8];
            #pragma unroll
            for (int nt = 0; nt < 4; ++nt)
                acc[mt][nt] = __builtin_amdgcn_mfma_f32_16x16x32_bf16(Af, Bf[nt], acc[mt][nt], 0, 0, 0);
        }
    }

    // epilogue: bias + gelu + fp8, direct store (row = hidden ch, col = token)
    #pragma unroll
    for (int mt = 0; mt < 4; ++mt) {
        #pragma unroll
        for (int r = 0; r < 4; ++r) {
            const int mch = 64 * wv + 16 * mt + quad * 4 + r;
            const float bias = fb[mch];
            unsigned char* Dp = D + (((size_t)(b * 256 + mch)) << 16) + y * 256 + x0;
            #pragma unroll
            for (int nt = 0; nt < 4; ++nt) {
                float v = acc[mt][nt][r] + bias;
                Dp[nt * 16 + l15] = f32_to_fp8(gelu_f(v));
            }
        }
    }
}

// ---------------------------------------------------------------------------
// Kernel 4: depthwise 5x5 conv + GELU + residual add (image layout, fp8).
// 4 x-adjacent outputs/thread; two aligned float4 LDS loads per tap-row.
// ---------------------------------------------------------------------------
__global__ __launch_bounds__(256) void k_dwconv(const unsigned char* __restrict__ D,
        const float* __restrict__ dww, const float* __restrict__ dwb,
        unsigned char* __restrict__ E) {
    __shared__ float sm[20 * 68];
    const int tid = threadIdx.x, gid = blockIdx.x;
    const int xt = gid & 3, yt = (gid >> 2) & 15, pc = gid >> 6;
    const int ch = pc & 255;
    const int x0 = xt * 64, y0 = yt * 16;
    const unsigned char* Dp = D + ((size_t)pc << 16);
    for (int idx = tid; idx < 20 * 68; idx += 256) {
        int r = idx / 68, cc = idx - r * 68;
        int gy = y0 + r - 2, gx = x0 + cc - 2;
        float v = 0.f;
        if (gy >= 0 && gy < 256 && gx >= 0 && gx < 256)
            v = fp8_to_f32(Dp[gy * 256 + gx]);
        sm[idx] = v;
    }
    float wr[25];
    #pragma unroll
    for (int k = 0; k < 25; ++k) wr[k] = dww[ch * 25 + k];   // block-uniform
    const float bb = dwb[ch];
    __syncthreads();
    const int xq = tid & 15, yl = tid >> 4;     // output (y0+yl, x0+4xq..+3)
    float a0 = bb, a1 = bb, a2 = bb, a3 = bb;
    float c0 = 0.f, c1 = 0.f, c2 = 0.f, c3 = 0.f;
    #pragma unroll
    for (int ky = 0; ky < 5; ++ky) {
        const float* rowp = &sm[(yl + ky) * 68 + 4 * xq];
        float4 lo = *(const float4*)rowp;
        float4 hi = *(const float4*)(rowp + 4);
        float v[8] = {lo.x, lo.y, lo.z, lo.w, hi.x, hi.y, hi.z, hi.w};
        if (ky == 2) { c0 = v[2]; c1 = v[3]; c2 = v[4]; c3 = v[5]; }
        #pragma unroll
        for (int kx = 0; kx < 5; ++kx) {
            const float w = wr[ky * 5 + kx];
            a0 += w * v[kx];     a1 += w * v[kx + 1];
            a2 += w * v[kx + 2]; a3 += w * v[kx + 3];
        }
    }
    uchar4 o;
    o.x = f32_to_fp8(c0 + gelu_f(a0));
    o.y = f32_to_fp8(c1 + gelu_f(a1));
    o.z = f32_to_fp8(c2 + gelu_f(a2));
    o.w = f32_to_fp8(c3 + gelu_f(a3));
    *(uchar4*)&E[((size_t)pc << 16) + (y0 + yl) * 256 + x0 + 4 * xq] = o;
}

// ---------------------------------------------------------------------------
// Kernel 5: fc2 + bias + residual + transpose -> out (b,c,h,w) fp32, MFMA.
// fc2w staged from k_cvt's bf16 copy (b128, no conversions).
// ---------------------------------------------------------------------------
__global__ __launch_bounds__(256) void k_fc2(const unsigned char* __restrict__ E,
        const unsigned short* __restrict__ Cb, const unsigned short* __restrict__ fc2w_bf,
        const float* __restrict__ fc2b, float* __restrict__ out) {
    __shared__ __align__(16) unsigned short Hb[64 * 136];   // [tok][k128 swz]
    __shared__ __align__(16) unsigned short Wb2[64 * 264];  // [oc][k256]
    __shared__ __align__(16) unsigned short Cl[64 * 72];    // residual raw bf16
    __shared__ float fbl[64];
    const int tid = threadIdx.x, gid = blockIdx.x;
    const int xc = gid & 3, y = (gid >> 2) & 255, b = gid >> 10;
    const int x0 = xc * 64;
    const int lane = tid & 63, wv = tid >> 6;
    const int l15 = lane & 15, quad = lane >> 4;
    const f32x4 zz = {0.f, 0.f, 0.f, 0.f};

    if (tid < 64) fbl[tid] = fc2b[tid];
    // stage residual (raw bf16 copy, coalesced)
    {
        const unsigned short* Cp = Cb + ((size_t)(b << 16) + y * 256 + x0) * 64;
        #pragma unroll
        for (int it = 0; it < 16; ++it) {
            int tt = wv + 4 * it;
            Cl[tt * 72 + lane] = Cp[tt * 64 + lane];
        }
    }
    // stage fc2w_bf -> Wb2 (b128 copies)
    {
        const ushortx8* w8 = (const ushortx8*)fc2w_bf;
        #pragma unroll
        for (int it = 0; it < 8; ++it) {
            int idx = it * 256 + tid;               // granule 0..2047
            int row = idx >> 5, c8 = idx & 31;      // 64 rows x 32 granules
            *(ushortx8*)&Wb2[row * 264 + c8 * 8] = w8[idx];
        }
    }

    f32x4 acc[4];
    #pragma unroll
    for (int nt = 0; nt < 4; ++nt) acc[nt] = zz;

    const int ldc = tid >> 4;           // 0..15: channel sub-index for loads
    const int tq  = tid & 15;           // token quad
    uchar4 u0[8];
    // prefetch chunk 0
    #pragma unroll
    for (int it = 0; it < 8; ++it) {
        int chl = ldc + 16 * it;        // 0..127
        u0[it] = *(const uchar4*)&E[(((size_t)(b * 256 + chl)) << 16) + y * 256 + x0 + 4 * tq];
    }
    __syncthreads();                    // Cl, Wb2 visible

    for (int kc = 0; kc < 2; ++kc) {
        // scatter chunk into Hb with granule swizzle
        #pragma unroll
        for (int it = 0; it < 8; ++it) {
            int chl = ldc + 16 * it;
            uchar4 u = u0[it];
            #pragma unroll
            for (int j = 0; j < 4; ++j) {
                int tok = 4 * tq + j;
                unsigned char uv = (j == 0) ? u.x : (j == 1) ? u.y : (j == 2) ? u.z : u.w;
                int pos = (((chl >> 3) ^ (tok >> 2)) << 3) + (chl & 7);
                Hb[tok * 136 + pos] = f2bf(fp8_to_f32(uv));
            }
        }
        // prefetch chunk 1 while chunk 0 computes
        if (kc == 0) {
            #pragma unroll
            for (int it = 0; it < 8; ++it) {
                int chl = ldc + 16 * it + 128;
                u0[it] = *(const uchar4*)&E[(((size_t)(b * 256 + chl)) << 16) + y * 256 + x0 + 4 * tq];
            }
        }
        __syncthreads();
        // MFMA over this 128-K chunk
        #pragma unroll
        for (int k32 = 0; k32 < 4; ++k32) {
            bf16x8 Af = *(const bf16x8*)&Wb2[(16 * wv + l15) * 264 + kc * 128 + k32 * 32 + quad * 8];
            const int g = k32 * 4 + quad;
            #pragma unroll
            for (int nt = 0; nt < 4; ++nt) {
                const int tok = nt * 16 + l15;
                bf16x8 Bf = *(const bf16x8*)&Hb[tok * 136 + ((g ^ (tok >> 2)) << 3)];
                acc[nt] = __builtin_amdgcn_mfma_f32_16x16x32_bf16(Af, Bf, acc[nt], 0, 0, 0);
            }
        }
        if (kc == 0) __syncthreads();   // before overwriting Hb
    }

    // epilogue: bias + residual, direct fp32 store (row = oc, col = token)
    #pragma unroll
    for (int r = 0; r < 4; ++r) {
        const int oc = 16 * wv + quad * 4 + r;
        const float bias = fbl[oc];
        float* op = out + (((size_t)(b * 64 + oc)) << 16) + y * 256 + x0;
        #pragma unroll
        for (int nt = 0; nt < 4; ++nt) {
            const int tok = nt * 16 + l15;
            op[tok] = acc[nt][r] + bias + bf2f(Cl[tok * 72 + oc]);
        }
    }
}

// ---------------------------------------------------------------------------
extern "C" void kernel_launch(void* const* d_in, const int* in_sizes, int n_in,
                              void* d_out, int out_size, void* d_ws, size_t ws_size,
                              hipStream_t stream) {
    const float* x     = (const float*)d_in[0];
    const float* n1w   = (const float*)d_in[1];
    const float* n1b   = (const float*)d_in[2];
    const float* qkvw  = (const float*)d_in[3];
    const float* qkvb  = (const float*)d_in[4];
    const float* rpb   = (const float*)d_in[5];
    const float* projw = (const float*)d_in[6];
    const float* projb = (const float*)d_in[7];
    const float* n2w   = (const float*)d_in[8];
    const float* n2b   = (const float*)d_in[9];
    const float* fc1w  = (const float*)d_in[10];
    const float* fc1b  = (const float*)d_in[11];
    const float* dww   = (const float*)d_in[12];
    const float* dwb   = (const float*)d_in[13];
    const float* fc2w  = (const float*)d_in[14];
    const float* fc2b  = (const float*)d_in[15];
    float* out = (float*)d_out;

    char* ws = (char*)d_ws;
    const size_t MB = 1048576;
    unsigned short* Cbuf = (unsigned short*)ws;                  // [0,32M)
    unsigned short* Ab   = (unsigned short*)(ws + 32 * MB);      // [32,64M)
    unsigned short* Bwp  = (unsigned short*)(ws + 64 * MB);      // [64,96M)
    unsigned char*  Dh   = (unsigned char*)(ws + 32 * MB);       // [32,96M)  alias A+Bw
    unsigned char*  Eh   = (unsigned char*)(ws + 96 * MB);       // [96,160M)

    // bf16 weight staging areas (inside E region, consumed by k2/k3 BEFORE k4
    // writes E; fc2w_bf in the dead D region, written after k4, read by k5)
    unsigned short* qkvw_bf = (unsigned short*)(ws + 96 * MB);
    unsigned short* projw_bf = (unsigned short*)(ws + 96 * MB + 24576);
    unsigned short* rpb_bf   = (unsigned short*)(ws + 96 * MB + 32768);
    unsigned short* fc1w_bf  = (unsigned short*)(ws + 96 * MB + 34816);
    unsigned short* fc2w_bf  = (unsigned short*)(ws + 32 * MB);

    k_prep  <<<64,    256, 0, stream>>>(qkvw, projw, rpb, fc1w,
                                        qkvw_bf, projw_bf, rpb_bf, fc1w_bf);
    k_ln1   <<<4096,  256, 0, stream>>>(x, n1w, n1b, Ab, Bwp);
    k_attn  <<<4096,  256, 0, stream>>>(Bwp, qkvw_bf, projw_bf, rpb_bf,
                                        qkvb, projb, Ab, Cbuf);
    k_ln2fc1<<<4096,  256, 0, stream>>>(Cbuf, n2w, n2b, fc1w_bf, fc1b, Dh);
    k_dwconv<<<65536, 256, 0, stream>>>(Dh, dww, dwb, Eh);
    k_cvt   <<<64,    256, 0, stream>>>(fc2w, fc2w_bf, 16384);
    k_fc2   <<<4096,  256, 0, stream>>>(Eh, Cbuf, fc2w_bf, fc2b, out);
}

// Round 2
// 427.015 us; speedup vs baseline: 1.3971x; 1.1153x over previous
//
#include <hip/hip_runtime.h>
#include <hip/hip_bf16.h>
#include <hip/hip_fp8.h>
#include <math.h>

// Problem constants: b=4, c=64, h=w=256, WS=8, SHIFT=4, HEADS=4, d=16, hidden=256
// Windows: 32x32 per image * 4 images = 4096; 64 tokens/window.
//
// Workspace layout (peak 160 MB):
//   Cb  bf16 32MB [0,32M)    x3 token-major        written k2, read k3+k5
//   A   bf16 32MB [32,64M)   shortcut token-major  written k1, read k2 (dead after)
//   Bw  bf16 32MB [64,96M)   shifted windows       written k1, read k2 (dead after)
//   D   fp8  64MB [32,96M)   hid image layout      written k3 (aliases A+Bw), read k4
//   E   fp8  64MB [96,160M)  hid+conv image layout written k4, read k5
//   Wbf bf16 ~66KB at [96M, 96M+66K): prep-converted qkvw/projw/rpb/fc1w,
//       read by k2/k3, then overwritten by k4's E write (safe: stream order).
//   fc2w_bf at [32M): written by k_cvt AFTER k4 (D dead), read k5.

typedef __bf16  bf16x8  __attribute__((ext_vector_type(8)));
typedef float   f32x4   __attribute__((ext_vector_type(4)));
typedef float   f32x2   __attribute__((ext_vector_type(2)));
typedef unsigned short ushortx8 __attribute__((ext_vector_type(8)));

__device__ __forceinline__ float gelu_f(float v) {
    // tanh-form gelu: 0.5v(1+tanh(0.79788456(v+0.044715v^3))) = v - v/(e^u+1)
    // with u = 1.5957691216 v + 0.0713548354 v^3. |err| <~2e-3, << fp8 step.
    float u = v * fmaf(0.0713548354f, v * v, 1.5957691216f);
    float t = __expf(u);                        // t=inf -> rcp=0 -> v;  t=0 -> v-v=0
    float r = __builtin_amdgcn_rcpf(t + 1.0f);
    return v - v * r;
}
__device__ __forceinline__ unsigned char f32_to_fp8(float v) {
    __hip_fp8_e4m3 t(v);
    return (unsigned char)t.__x;
}
__device__ __forceinline__ float fp8_to_f32(unsigned char u) {
    __hip_fp8_e4m3 t;
    t.__x = (__hip_fp8_storage_t)u;
    return (float)t;
}

// Hardware packed fp8 (OCP e4m3 on gfx950) converters; sw fallback if absent.
#if __has_builtin(__builtin_amdgcn_cvt_pk_f32_fp8) && __has_builtin(__builtin_amdgcn_cvt_pk_fp8_f32)
#define HW_FP8 1
#endif
template<bool HI>
__device__ __forceinline__ f32x2 fp8x2_f32(unsigned int u) {
#ifdef HW_FP8
    return __builtin_amdgcn_cvt_pk_f32_fp8((int)u, HI);
#else
    f32x2 r;
    const int s = HI ? 16 : 0;
    r.x = fp8_to_f32((unsigned char)(u >> s));
    r.y = fp8_to_f32((unsigned char)(u >> (s + 8)));
    return r;
#endif
}
template<bool HI>
__device__ __forceinline__ unsigned int f32x2_fp8(float a, float b, unsigned int old) {
#ifdef HW_FP8
    return (unsigned int)__builtin_amdgcn_cvt_pk_fp8_f32(a, b, (int)old, HI);
#else
    unsigned int v = (unsigned int)f32_to_fp8(a) | ((unsigned int)f32_to_fp8(b) << 8);
    return HI ? ((old & 0x0000ffffu) | (v << 16)) : ((old & 0xffff0000u) | v);
#endif
}

__device__ __forceinline__ unsigned short f2bf(float f) {   // RNE, matches HW
    unsigned int u = __builtin_bit_cast(unsigned int, f);
    u += 0x7fffu + ((u >> 16) & 1u);
    return (unsigned short)(u >> 16);
}
__device__ __forceinline__ float bf2f(unsigned short u) {
    return __builtin_bit_cast(float, ((unsigned int)u) << 16);
}

// ---------------------------------------------------------------------------
// Kernel 0: one-time weight conversion to bf16 (amortizes 4096 blocks' worth
// of per-block fp32 loads + f2bf conversions in k2/k3).
// ---------------------------------------------------------------------------
__global__ __launch_bounds__(256) void k_prep(
        const float* __restrict__ qkvw, const float* __restrict__ projw,
        const float* __restrict__ rpb,  const float* __restrict__ fc1w,
        unsigned short* __restrict__ qkvw_bf, unsigned short* __restrict__ projw_bf,
        unsigned short* __restrict__ rpb_bf,  unsigned short* __restrict__ fc1w_bf) {
    const int i = blockIdx.x * 256 + threadIdx.x;   // grid 64*256 = 16384
    if (i < 12288) qkvw_bf[i] = f2bf(qkvw[i]);
    if (i < 4096)  projw_bf[i] = f2bf(projw[i]);
    if (i < 900)   rpb_bf[i]   = f2bf(rpb[i]);
    if (i < 16384) fc1w_bf[i]  = f2bf(fc1w[i]);
}

__global__ __launch_bounds__(256) void k_cvt(const float* __restrict__ src,
        unsigned short* __restrict__ dst, int n) {
    const int i = blockIdx.x * 256 + threadIdx.x;
    if (i < n) dst[i] = f2bf(src[i]);
}

// ---------------------------------------------------------------------------
// Kernel 1: LN1 + transpose. Reads x (b,c,h,w). Writes:
//   A  : shortcut, token-major bf16 [b*65536 tokens][64 ch]
//   Bw : normalized, shifted+window-partitioned bf16 [4096 win][64 tok][64 ch]
// ---------------------------------------------------------------------------
__global__ __launch_bounds__(256) void k_ln1(const float* __restrict__ x,
        const float* __restrict__ w1, const float* __restrict__ b1,
        unsigned short* __restrict__ A, unsigned short* __restrict__ Bw) {
    __shared__ float tile[64 * 65];           // [ch][token]
    __shared__ float red0[256], red1[256];
    __shared__ float muv[64], rsv[64], lw[64], lb[64];
    const int tid = threadIdx.x;
    const int gid = blockIdx.x;
    const int xc = gid & 3, y = (gid >> 2) & 255, b = gid >> 10;
    const int x0 = xc * 64;
    if (tid < 64) { lw[tid] = w1[tid]; lb[tid] = b1[tid]; }

    const float* xb = x + ((size_t)b * 64) * 65536 + y * 256 + x0;
    {
        const int tk = tid & 63, cl = tid >> 6;
        for (int it = 0; it < 16; ++it) {
            int cc = cl + 4 * it;
            tile[cc * 65 + tk] = xb[(size_t)cc * 65536 + tk];   // coalesced
        }
    }
    __syncthreads();
    {
        const int tk = tid & 63, cl = tid >> 6;
        float s = 0.f, s2 = 0.f;
        #pragma unroll
        for (int k = 0; k < 16; ++k) {
            float v = tile[(cl * 16 + k) * 65 + tk];
            s += v; s2 += v * v;
        }
        red0[cl * 64 + tk] = s; red1[cl * 64 + tk] = s2;
    }
    __syncthreads();
    if (tid < 64) {
        float s  = red0[tid] + red0[64 + tid] + red0[128 + tid] + red0[192 + tid];
        float s2 = red1[tid] + red1[64 + tid] + red1[128 + tid] + red1[192 + tid];
        float mu = s * (1.f / 64.f);
        float var = s2 * (1.f / 64.f) - mu * mu;
        muv[tid] = mu; rsv[tid] = rsqrtf(var + 1e-5f);
    }
    __syncthreads();
    const int ch = tid & 63, tl = tid >> 6;
    const int ys = (y + 252) & 255;          // shifted row (roll -4)
    const int wy = ys >> 3, py = ys & 7;
    for (int it = 0; it < 16; ++it) {
        int t = tl + 4 * it;
        float v = tile[ch * 65 + t];         // stride 65 -> free 2-way
        int tok = (b << 16) + y * 256 + x0 + t;
        A[(size_t)tok * 64 + ch] = f2bf(v);
        float vn = (v - muv[t]) * rsv[t] * lw[ch] + lb[ch];
        int xs = (x0 + t + 252) & 255;
        int wx = xs >> 3, px = xs & 7;
        int widx = (b << 10) + (wy << 5) + wx;
        int pos = (py << 3) + px;
        Bw[((size_t)widx * 64 + pos) * 64 + ch] = f2bf(vn);
    }
}

// ---------------------------------------------------------------------------
// Kernel 2: windowed attention, MFMA bf16 (structure as R1: 5 barriers,
// bf16 weights from prep, LDS reuse, edge-window mask skip, unnormalized P).
// ---------------------------------------------------------------------------
__global__ __launch_bounds__(256) void k_attn(
        const unsigned short* __restrict__ Bw,
        const unsigned short* __restrict__ qkvw_bf,
        const unsigned short* __restrict__ projw_bf,
        const unsigned short* __restrict__ rpb_bf,
        const float* __restrict__ qkvb,
        const float* __restrict__ projb,
        const unsigned short* __restrict__ A, unsigned short* __restrict__ Cb) {
    __shared__ __align__(16) unsigned short Xs[4608];    // [64][72] X; later o
    __shared__ __align__(16) unsigned short Ws[13824];   // [192][72] W; then QKV/P/projw
    __shared__ __align__(8)  unsigned short rpbl[900];
    __shared__ float qkvbl[192];
    __shared__ float projbl[64];

    const int tid = threadIdx.x;
    const int lane = tid & 63, wv = tid >> 6;
    const int l15 = lane & 15, quad = lane >> 4;
    const int widx = blockIdx.x;
    const int wib = widx & 1023;
    const int wy = wib >> 5, wx = wib & 31, bimg = widx >> 10;
    const bool edge = (wy == 31) | (wx == 31);   // only these windows have a mask

    const f32x4 zz = {0.f, 0.f, 0.f, 0.f};
    const ushortx8 zu = {0, 0, 0, 0, 0, 0, 0, 0};
    const bf16x8 z8 = __builtin_bit_cast(bf16x8, zu);

    // prefetch projw (2 granules/thread) — consumed after the post-S barrier
    const ushortx8 pw0 = *(const ushortx8*)(projw_bf + tid * 8);
    const ushortx8 pw1 = *(const ushortx8*)(projw_bf + (256 + tid) * 8);

    // stage X: each wave stages its OWN 16 token rows (wave-private)
    {
        const unsigned short* Xg = Bw + (size_t)widx * 4096 + wv * 1024;
        #pragma unroll
        for (int it = 0; it < 2; ++it) {
            int g = it * 64 + lane;                 // granule 0..127
            int row = g >> 3, c8 = g & 7;
            *(ushortx8*)&Xs[(wv * 16 + row) * 72 + c8 * 8] =
                *(const ushortx8*)(Xg + g * 8);
        }
    }
    // stage full qkvw (192 rows, cooperative, b128)
    #pragma unroll
    for (int it = 0; it < 6; ++it) {
        int g = it * 256 + tid;                     // granule 0..1535
        int row = g >> 3, c8 = g & 7;
        *(ushortx8*)&Ws[row * 72 + c8 * 8] = *(const ushortx8*)(qkvw_bf + g * 8);
    }
    if (tid < 225) *(uint2*)&rpbl[tid * 4] = *(const uint2*)(rpb_bf + tid * 4);
    if (tid < 192) qkvbl[tid] = qkvb[tid];
    if (tid < 64)  projbl[tid] = projb[tid];
    __syncthreads();                                // B1

    // QKV: 24 MFMA/thread (A = own 16 token rows of X, B = all 192 W rows)
    f32x4 qacc[12];
    #pragma unroll
    for (int i = 0; i < 12; ++i) qacc[i] = zz;
    {
        const bf16x8 av0 = *(const bf16x8*)&Xs[(16 * wv + l15) * 72 + quad * 8];
        const bf16x8 av1 = *(const bf16x8*)&Xs[(16 * wv + l15) * 72 + 32 + quad * 8];
        #pragma unroll
        for (int gl = 0; gl < 12; ++gl) {
            bf16x8 bv0 = *(const bf16x8*)&Ws[(gl * 16 + l15) * 72 + quad * 8];
            qacc[gl] = __builtin_amdgcn_mfma_f32_16x16x32_bf16(av0, bv0, qacc[gl], 0, 0, 0);
            bf16x8 bv1 = *(const bf16x8*)&Ws[(gl * 16 + l15) * 72 + 32 + quad * 8];
            qacc[gl] = __builtin_amdgcn_mfma_f32_16x16x32_bf16(av1, bv1, qacc[gl], 0, 0, 0);
        }
    }
    __syncthreads();                                // B2 (all W reads done)

    // write Q (scaled) / K / V into Ws
    #pragma unroll
    for (int g = 0; g < 12; ++g) {
        #pragma unroll
        for (int r = 0; r < 4; ++r) {
            int tok = 16 * wv + quad * 4 + r;
            int oc  = g * 16 + l15;
            float v = qacc[g][r] + qkvbl[oc];
            if (g < 4)       Ws[g * 1024 + tok * 16 + l15] = f2bf(v * 0.25f);
            else if (g < 8)  Ws[4096 + (g - 4) * 1024 + tok * 16 + l15] = f2bf(v);
            else             Ws[8192 + ((g - 8) * 16 + l15) * 72 + tok] = f2bf(v);
        }
    }
    __syncthreads();                                // B3

    // S = Q K^T  (16 MFMA/thread)
    f32x4 sacc[4][4];
    #pragma unroll
    for (int h = 0; h < 4; ++h) {
        bf16x8 qa = z8;
        if (quad < 2) qa = *(const bf16x8*)&Ws[h * 1024 + (16 * wv + l15) * 16 + quad * 8];
        #pragma unroll
        for (int nt = 0; nt < 4; ++nt) {
            bf16x8 kf = z8;
            if (quad < 2) kf = *(const bf16x8*)&Ws[4096 + h * 1024 + (nt * 16 + l15) * 16 + quad * 8];
            sacc[h][nt] = __builtin_amdgcn_mfma_f32_16x16x32_bf16(qa, kf, zz, 0, 0, 0);
        }
    }
    __syncthreads();                                // B4 (Q/K reads done)

    // stage projw into the dead K region, XOR-swizzled [oc][64]
    {
        const int r0 = tid >> 3;
        *(ushortx8*)&Ws[4096 + r0 * 64 + (((tid & 7) ^ (r0 & 7)) << 3)] = pw0;
        const int g1 = 256 + tid, r1 = g1 >> 3;
        *(ushortx8*)&Ws[4096 + r1 * 64 + (((g1 & 7) ^ (r1 & 7)) << 3)] = pw1;
    }

    // per-thread j constants
    const int jhi = l15 >> 3, jlo = l15 & 7;
    int offj4[4], regj[4];
    #pragma unroll
    for (int nt = 0; nt < 4; ++nt) {
        int j = nt * 16 + l15;
        int jy = j >> 3, jx = j & 7;
        offj4[nt] = (jy * 15 + jx) * 4;
        regj[nt] = 0;
        if (edge) {
            int ysj = wy * 8 + jy, xsj = wx * 8 + jx;
            regj[nt] = (ysj >= 252 ? 2 : (ysj >= 248 ? 1 : 0)) * 3
                     + (xsj >= 252 ? 2 : (xsj >= 248 ? 1 : 0));
        }
    }
    // per-r constants
    int rbA[4], regiA[4], pbaseA[4], i7A[4];
    #pragma unroll
    for (int r = 0; r < 4; ++r) {
        const int i = 16 * wv + quad * 4 + r;
        const int iy = i >> 3, ix = i & 7;
        rbA[r] = ((iy + 7) * 15 + (ix + 7)) * 4;
        i7A[r] = i & 7;
        pbaseA[r] = i * 64 + jlo;
        regiA[r] = 0;
        if (edge) {
            const int ysi = wy * 8 + iy, xsi = wx * 8 + ix;
            regiA[r] = (ysi >= 252 ? 2 : (ysi >= 248 ? 1 : 0)) * 3
                     + (xsi >= 252 ? 2 : (xsi >= 248 ? 1 : 0));
        }
    }

    // per-head: softmax (P unnormalized into swizzled Q region) + PV
    f32x4 o[4];
    #pragma unroll
    for (int h = 0; h < 4; ++h) {
        float invh[4];
        #pragma unroll
        for (int r = 0; r < 4; ++r) {
            float m0 = -1e30f;
            #pragma unroll
            for (int nt = 0; nt < 4; ++nt) {
                float s = sacc[h][nt][r] + bf2f(rpbl[rbA[r] + h - offj4[nt]]);
                if (edge) s += (regj[nt] == regiA[r]) ? 0.f : -100.f;
                sacc[h][nt][r] = s;
                m0 = fmaxf(m0, s);
            }
            m0 = fmaxf(m0, __shfl_xor(m0, 1));
            m0 = fmaxf(m0, __shfl_xor(m0, 2));
            m0 = fmaxf(m0, __shfl_xor(m0, 4));
            m0 = fmaxf(m0, __shfl_xor(m0, 8));
            float s0 = 0.f;
            #pragma unroll
            for (int nt = 0; nt < 4; ++nt) {
                float e = __expf(sacc[h][nt][r] - m0);
                s0 += e;
                Ws[pbaseA[r] + ((((nt << 1) | jhi) ^ i7A[r]) << 3)] = f2bf(e);
            }
            s0 += __shfl_xor(s0, 1); s0 += __shfl_xor(s0, 2);
            s0 += __shfl_xor(s0, 4); s0 += __shfl_xor(s0, 8);
            invh[r] = 1.f / s0;
        }
        o[h] = zz;
        #pragma unroll
        for (int s = 0; s < 2; ++s) {
            bf16x8 pa = *(const bf16x8*)&Ws[(16 * wv + l15) * 64
                                            + (((s * 4 + quad) ^ (l15 & 7)) << 3)];
            bf16x8 vb = *(const bf16x8*)&Ws[8192 + (h * 16 + l15) * 72 + s * 32 + quad * 8];
            o[h] = __builtin_amdgcn_mfma_f32_16x16x32_bf16(pa, vb, o[h], 0, 0, 0);
        }
        #pragma unroll
        for (int r = 0; r < 4; ++r) o[h][r] *= invh[r];
    }

    // prefetch residual A values (consumed in epilogue; hidden under B5 + proj MFMA)
    unsigned short resid[16];
    #pragma unroll
    for (int r = 0; r < 4; ++r) {
        int tok = 16 * wv + quad * 4 + r;
        int py = tok >> 3, px = tok & 7;
        int yo = (wy * 8 + py + 4) & 255, xo = (wx * 8 + px + 4) & 255;
        size_t gt = ((size_t)bimg << 16) + yo * 256 + xo;
        #pragma unroll
        for (int nt = 0; nt < 4; ++nt)
            resid[r * 4 + nt] = A[gt * 64 + nt * 16 + l15];
    }

    // o -> Xs (own rows only; Xs dead since QKV)
    #pragma unroll
    for (int h = 0; h < 4; ++h)
        #pragma unroll
        for (int r = 0; r < 4; ++r)
            Xs[(16 * wv + quad * 4 + r) * 72 + h * 16 + l15] = f2bf(o[h][r]);
    __syncthreads();                                // B5 (projw + o visible)

    // proj: 8 MFMA/thread
    f32x4 pacc[4];
    #pragma unroll
    for (int nt = 0; nt < 4; ++nt) {
        pacc[nt] = zz;
        #pragma unroll
        for (int s = 0; s < 2; ++s) {
            bf16x8 oa = *(const bf16x8*)&Xs[(16 * wv + l15) * 72 + s * 32 + quad * 8];
            bf16x8 wb = *(const bf16x8*)&Ws[4096 + (nt * 16 + l15) * 64
                                            + (((s * 4 + quad) ^ (l15 & 7)) << 3)];
            pacc[nt] = __builtin_amdgcn_mfma_f32_16x16x32_bf16(oa, wb, pacc[nt], 0, 0, 0);
        }
    }

    // epilogue: bias + residual, un-shift, store Cb
    #pragma unroll
    for (int r = 0; r < 4; ++r) {
        int tok = 16 * wv + quad * 4 + r;
        int py = tok >> 3, px = tok & 7;
        int yo = (wy * 8 + py + 4) & 255, xo = (wx * 8 + px + 4) & 255;
        size_t gt = ((size_t)bimg << 16) + yo * 256 + xo;
        #pragma unroll
        for (int nt = 0; nt < 4; ++nt) {
            int oc = nt * 16 + l15;
            float v = pacc[nt][r] + projbl[oc] + bf2f(resid[r * 4 + nt]);
            Cb[gt * 64 + oc] = f2bf(v);
        }
    }
}

// ---------------------------------------------------------------------------
// Kernel 3: LN2 + fc1 + GELU -> D (image layout fp8), MFMA bf16.
// fc1w staged from prep's bf16 copy (b128); packed HW fp8 store.
// ---------------------------------------------------------------------------
__global__ __launch_bounds__(256) void k_ln2fc1(const unsigned short* __restrict__ Cb,
        const float* __restrict__ w2, const float* __restrict__ b2,
        const unsigned short* __restrict__ fc1w_bf, const float* __restrict__ fc1b,
        unsigned char* __restrict__ D) {
    __shared__ __align__(16) unsigned short Xb[64 * 72];    // raw->normalized bf16
    __shared__ __align__(16) unsigned short Wb[256 * 72];   // fc1w bf16
    __shared__ float red0[256], red1[256];
    __shared__ float muv[64], rsv[64], lwv[64], lbv[64], fb[256];
    const int tid = threadIdx.x, gid = blockIdx.x;
    const int xc = gid & 3, y = (gid >> 2) & 255, b = gid >> 10;
    const int x0 = xc * 64;
    const int lane = tid & 63, wv = tid >> 6;
    const int l15 = lane & 15, quad = lane >> 4;
    const f32x4 zz = {0.f, 0.f, 0.f, 0.f};

    if (tid < 64) { lwv[tid] = w2[tid]; lbv[tid] = b2[tid]; }
    fb[tid] = fc1b[tid];

    // stage Cb -> Xb (raw bf16, coalesced)
    const unsigned short* Cp = Cb + ((size_t)(b << 16) + y * 256 + x0) * 64;
    #pragma unroll
    for (int it = 0; it < 16; ++it) {
        int tt = wv + 4 * it;
        Xb[tt * 72 + lane] = Cp[tt * 64 + lane];
    }
    // stage fc1w_bf -> Wb (b128 copies)
    {
        const ushortx8* w8 = (const ushortx8*)fc1w_bf;
        #pragma unroll
        for (int it = 0; it < 8; ++it) {
            int idx = it * 256 + tid;               // granule 0..2047
            int row = idx >> 3, c8 = idx & 7;
            *(ushortx8*)&Wb[row * 72 + c8 * 8] = w8[idx];
        }
    }
    __syncthreads();
    // LN stats from bf16 tile
    {
        const int tok = tid & 63, cl = tid >> 6;
        float s = 0.f, s2 = 0.f;
        #pragma unroll
        for (int g = 0; g < 2; ++g) {
            const ushortx8 u = *(const ushortx8*)&Xb[tok * 72 + cl * 16 + g * 8];
            #pragma unroll
            for (int k = 0; k < 8; ++k) { float v = bf2f(u[k]); s += v; s2 += v * v; }
        }
        red0[cl * 64 + tok] = s; red1[cl * 64 + tok] = s2;
    }
    __syncthreads();
    if (tid < 64) {
        float s  = red0[tid] + red0[64 + tid] + red0[128 + tid] + red0[192 + tid];
        float s2 = red1[tid] + red1[64 + tid] + red1[128 + tid] + red1[192 + tid];
        float mu = s * (1.f / 64.f);
        float var = s2 * (1.f / 64.f) - mu * mu;
        muv[tid] = mu; rsv[tid] = rsqrtf(var + 1e-5f);
    }
    __syncthreads();
    // normalize in place
    #pragma unroll
    for (int it = 0; it < 16; ++it) {
        int tt = wv + 4 * it;
        float v = bf2f(Xb[tt * 72 + lane]);
        v = (v - muv[tt]) * rsv[tt] * lwv[lane] + lbv[lane];
        Xb[tt * 72 + lane] = f2bf(v);
    }
    __syncthreads();

    // MFMA: acc[mt][nt], m = 64wv+16mt (hidden ch), n = 16nt (token), K=64
    f32x4 acc[4][4];
    #pragma unroll
    for (int mt = 0; mt < 4; ++mt)
        #pragma unroll
        for (int nt = 0; nt < 4; ++nt) acc[mt][nt] = zz;
    #pragma unroll
    for (int s = 0; s < 2; ++s) {
        bf16x8 Bf[4];
        #pragma unroll
        for (int nt = 0; nt < 4; ++nt)
            Bf[nt] = *(const bf16x8*)&Xb[(nt * 16 + l15) * 72 + s * 32 + quad * 8];
        #pragma unroll
        for (int mt = 0; mt < 4; ++mt) {
            bf16x8 Af = *(const bf16x8*)&Wb[(64 * wv + 16 * mt + l15) * 72 + s * 32 + quad * 8];
            #pragma unroll
            for (int nt = 0; nt < 4; ++nt)
                acc[mt][nt] = __builtin_amdgcn_mfma_f32_16x16x32_bf16(Af, Bf[nt], acc[mt][nt], 0, 0, 0);
        }
    }

    // epilogue: bias + gelu + packed fp8 cvt, byte stores (row = hidden ch)
    #pragma unroll
    for (int mt = 0; mt < 4; ++mt) {
        #pragma unroll
        for (int r = 0; r < 4; ++r) {
            const int mch = 64 * wv + 16 * mt + quad * 4 + r;
            const float bias = fb[mch];
            unsigned char* Dp = D + (((size_t)(b * 256 + mch)) << 16) + y * 256 + x0;
            float g0 = gelu_f(acc[mt][0][r] + bias);
            float g1 = gelu_f(acc[mt][1][r] + bias);
            float g2 = gelu_f(acc[mt][2][r] + bias);
            float g3 = gelu_f(acc[mt][3][r] + bias);
            unsigned int pk = f32x2_fp8<false>(g0, g1, 0u);
            pk = f32x2_fp8<true>(g2, g3, pk);
            Dp[l15]      = (unsigned char)(pk);
            Dp[16 + l15] = (unsigned char)(pk >> 8);
            Dp[32 + l15] = (unsigned char)(pk >> 16);
            Dp[48 + l15] = (unsigned char)(pk >> 24);
        }
    }
}

// ---------------------------------------------------------------------------
// Kernel 4: depthwise 5x5 conv + GELU + residual add (image layout, fp8).
// Restructured staging: 20 rows x 18 aligned uchar4 units, packed HW fp8->f32
// on stage (2 cvt_pk + 2 ds_write_b64 per unit), whole-unit OOB test (edge
// units are either fully in-bounds or fully dead). Packed fp8 store.
// ---------------------------------------------------------------------------
__global__ __launch_bounds__(256) void k_dwconv(const unsigned char* __restrict__ D,
        const float* __restrict__ dww, const float* __restrict__ dwb,
        unsigned char* __restrict__ E) {
    __shared__ __align__(16) float sm[20 * 68];     // [row][k], k -> gx = x0-2+k
    const int tid = threadIdx.x, gid = blockIdx.x;
    const int xt = gid & 3, yt = (gid >> 2) & 15, pc = gid >> 6;
    const int ch = pc & 255;
    const int x0 = xt * 64, y0 = yt * 16;
    const unsigned char* Dp = D + ((size_t)pc << 16);

    // stage: unit u = (r, c): r = 0..19 rows (gy = y0+r-2), c = 0..17 dwords
    // covering gx = x0-4+4c .. +3; staged k = 4c+j-2 clipped to [0,68).
    for (int u = tid; u < 360; u += 256) {
        const int r = u / 18, c = u - r * 18;
        const int gy = y0 + r - 2;
        const int gxb = x0 - 4 + 4 * c;
        f32x2 lo = {0.f, 0.f}, hi = {0.f, 0.f};
        if (((unsigned)gy < 256u) && ((unsigned)gxb < 256u)) {
            const unsigned int v = *(const unsigned int*)(Dp + gy * 256 + gxb);
            lo = fp8x2_f32<false>(v);
            hi = fp8x2_f32<true>(v);
        }
        float* row = &sm[r * 68];
        if (c == 0)       *(f32x2*)&row[0]  = hi;            // k=0,1  <- j=2,3
        else if (c == 17) *(f32x2*)&row[66] = lo;            // k=66,67<- j=0,1
        else { *(f32x2*)&row[4 * c - 2] = lo; *(f32x2*)&row[4 * c] = hi; }
    }
    float wr[25];
    #pragma unroll
    for (int k = 0; k < 25; ++k) wr[k] = dww[ch * 25 + k];   // block-uniform
    const float bb = dwb[ch];
    __syncthreads();
    const int xq = tid & 15, yl = tid >> 4;     // output (y0+yl, x0+4xq..+3)
    float a0 = bb, a1 = bb, a2 = bb, a3 = bb;
    float c0 = 0.f, c1 = 0.f, c2 = 0.f, c3 = 0.f;
    #pragma unroll
    for (int ky = 0; ky < 5; ++ky) {
        const float* rowp = &sm[(yl + ky) * 68 + 4 * xq];
        float4 lo = *(const float4*)rowp;
        float4 hi = *(const float4*)(rowp + 4);
        float v[8] = {lo.x, lo.y, lo.z, lo.w, hi.x, hi.y, hi.z, hi.w};
        if (ky == 2) { c0 = v[2]; c1 = v[3]; c2 = v[4]; c3 = v[5]; }
        #pragma unroll
        for (int kx = 0; kx < 5; ++kx) {
            const float w = wr[ky * 5 + kx];
            a0 += w * v[kx];     a1 += w * v[kx + 1];
            a2 += w * v[kx + 2]; a3 += w * v[kx + 3];
        }
    }
    unsigned int pk = f32x2_fp8<false>(c0 + gelu_f(a0), c1 + gelu_f(a1), 0u);
    pk = f32x2_fp8<true>(c2 + gelu_f(a2), c3 + gelu_f(a3), pk);
    *(unsigned int*)&E[((size_t)pc << 16) + (y0 + yl) * 256 + x0 + 4 * xq] = pk;
}

// ---------------------------------------------------------------------------
// Kernel 5: fc2 + bias + residual + transpose -> out (b,c,h,w) fp32, MFMA.
// fc2w staged from k_cvt's bf16 copy; packed HW fp8->f32 on E reads.
// ---------------------------------------------------------------------------
__global__ __launch_bounds__(256) void k_fc2(const unsigned char* __restrict__ E,
        const unsigned short* __restrict__ Cb, const unsigned short* __restrict__ fc2w_bf,
        const float* __restrict__ fc2b, float* __restrict__ out) {
    __shared__ __align__(16) unsigned short Hb[64 * 136];   // [tok][k128 swz]
    __shared__ __align__(16) unsigned short Wb2[64 * 264];  // [oc][k256]
    __shared__ __align__(16) unsigned short Cl[64 * 72];    // residual raw bf16
    __shared__ float fbl[64];
    const int tid = threadIdx.x, gid = blockIdx.x;
    const int xc = gid & 3, y = (gid >> 2) & 255, b = gid >> 10;
    const int x0 = xc * 64;
    const int lane = tid & 63, wv = tid >> 6;
    const int l15 = lane & 15, quad = lane >> 4;
    const f32x4 zz = {0.f, 0.f, 0.f, 0.f};

    if (tid < 64) fbl[tid] = fc2b[tid];
    // stage residual (raw bf16 copy, coalesced)
    {
        const unsigned short* Cp = Cb + ((size_t)(b << 16) + y * 256 + x0) * 64;
        #pragma unroll
        for (int it = 0; it < 16; ++it) {
            int tt = wv + 4 * it;
            Cl[tt * 72 + lane] = Cp[tt * 64 + lane];
        }
    }
    // stage fc2w_bf -> Wb2 (b128 copies)
    {
        const ushortx8* w8 = (const ushortx8*)fc2w_bf;
        #pragma unroll
        for (int it = 0; it < 8; ++it) {
            int idx = it * 256 + tid;               // granule 0..2047
            int row = idx >> 5, c8 = idx & 31;      // 64 rows x 32 granules
            *(ushortx8*)&Wb2[row * 264 + c8 * 8] = w8[idx];
        }
    }

    f32x4 acc[4];
    #pragma unroll
    for (int nt = 0; nt < 4; ++nt) acc[nt] = zz;

    const int ldc = tid >> 4;           // 0..15: channel sub-index for loads
    const int tq  = tid & 15;           // token quad
    unsigned int u0[8];
    // prefetch chunk 0
    #pragma unroll
    for (int it = 0; it < 8; ++it) {
        int chl = ldc + 16 * it;        // 0..127
        u0[it] = *(const unsigned int*)&E[(((size_t)(b * 256 + chl)) << 16) + y * 256 + x0 + 4 * tq];
    }
    __syncthreads();                    // Cl, Wb2 visible

    for (int kc = 0; kc < 2; ++kc) {
        // scatter chunk into Hb with granule swizzle (packed HW cvt)
        #pragma unroll
        for (int it = 0; it < 8; ++it) {
            int chl = ldc + 16 * it;
            int pos = ((chl >> 3) ^ 0) ;    // recomputed per token below
            f32x2 lo = fp8x2_f32<false>(u0[it]);
            f32x2 hi = fp8x2_f32<true>(u0[it]);
            float vals[4] = {lo.x, lo.y, hi.x, hi.y};
            #pragma unroll
            for (int j = 0; j < 4; ++j) {
                int tok = 4 * tq + j;
                int p = (((chl >> 3) ^ (tok >> 2)) << 3) + (chl & 7);
                Hb[tok * 136 + p] = f2bf(vals[j]);
            }
            (void)pos;
        }
        // prefetch chunk 1 while chunk 0 computes
        if (kc == 0) {
            #pragma unroll
            for (int it = 0; it < 8; ++it) {
                int chl = ldc + 16 * it + 128;
                u0[it] = *(const unsigned int*)&E[(((size_t)(b * 256 + chl)) << 16) + y * 256 + x0 + 4 * tq];
            }
        }
        __syncthreads();
        // MFMA over this 128-K chunk
        #pragma unroll
        for (int k32 = 0; k32 < 4; ++k32) {
            bf16x8 Af = *(const bf16x8*)&Wb2[(16 * wv + l15) * 264 + kc * 128 + k32 * 32 + quad * 8];
            const int g = k32 * 4 + quad;
            #pragma unroll
            for (int nt = 0; nt < 4; ++nt) {
                const int tok = nt * 16 + l15;
                bf16x8 Bf = *(const bf16x8*)&Hb[tok * 136 + ((g ^ (tok >> 2)) << 3)];
                acc[nt] = __builtin_amdgcn_mfma_f32_16x16x32_bf16(Af, Bf, acc[nt], 0, 0, 0);
            }
        }
        if (kc == 0) __syncthreads();   // before overwriting Hb
    }

    // epilogue: bias + residual, direct fp32 store (row = oc, col = token)
    #pragma unroll
    for (int r = 0; r < 4; ++r) {
        const int oc = 16 * wv + quad * 4 + r;
        const float bias = fbl[oc];
        float* op = out + (((size_t)(b * 64 + oc)) << 16) + y * 256 + x0;
        #pragma unroll
        for (int nt = 0; nt < 4; ++nt) {
            const int tok = nt * 16 + l15;
            op[tok] = acc[nt][r] + bias + bf2f(Cl[tok * 72 + oc]);
        }
    }
}

// ---------------------------------------------------------------------------
extern "C" void kernel_launch(void* const* d_in, const int* in_sizes, int n_in,
                              void* d_out, int out_size, void* d_ws, size_t ws_size,
                              hipStream_t stream) {
    const float* x     = (const float*)d_in[0];
    const float* n1w   = (const float*)d_in[1];
    const float* n1b   = (const float*)d_in[2];
    const float* qkvw  = (const float*)d_in[3];
    const float* qkvb  = (const float*)d_in[4];
    const float* rpb   = (const float*)d_in[5];
    const float* projw = (const float*)d_in[6];
    const float* projb = (const float*)d_in[7];
    const float* n2w   = (const float*)d_in[8];
    const float* n2b   = (const float*)d_in[9];
    const float* fc1w  = (const float*)d_in[10];
    const float* fc1b  = (const float*)d_in[11];
    const float* dww   = (const float*)d_in[12];
    const float* dwb   = (const float*)d_in[13];
    const float* fc2w  = (const float*)d_in[14];
    const float* fc2b  = (const float*)d_in[15];
    float* out = (float*)d_out;

    char* ws = (char*)d_ws;
    const size_t MB = 1048576;
    unsigned short* Cbuf = (unsigned short*)ws;                  // [0,32M)
    unsigned short* Ab   = (unsigned short*)(ws + 32 * MB);      // [32,64M)
    unsigned short* Bwp  = (unsigned short*)(ws + 64 * MB);      // [64,96M)
    unsigned char*  Dh   = (unsigned char*)(ws + 32 * MB);       // [32,96M)  alias A+Bw
    unsigned char*  Eh   = (unsigned char*)(ws + 96 * MB);       // [96,160M)

    // bf16 weight staging areas (inside E region, consumed by k2/k3 BEFORE k4
    // writes E; fc2w_bf in the dead D region, written after k4, read by k5)
    unsigned short* qkvw_bf = (unsigned short*)(ws + 96 * MB);
    unsigned short* projw_bf = (unsigned short*)(ws + 96 * MB + 24576);
    unsigned short* rpb_bf   = (unsigned short*)(ws + 96 * MB + 32768);
    unsigned short* fc1w_bf  = (unsigned short*)(ws + 96 * MB + 34816);
    unsigned short* fc2w_bf  = (unsigned short*)(ws + 32 * MB);

    k_prep  <<<64,    256, 0, stream>>>(qkvw, projw, rpb, fc1w,
                                        qkvw_bf, projw_bf, rpb_bf, fc1w_bf);
    k_ln1   <<<4096,  256, 0, stream>>>(x, n1w, n1b, Ab, Bwp);
    k_attn  <<<4096,  256, 0, stream>>>(Bwp, qkvw_bf, projw_bf, rpb_bf,
                                        qkvb, projb, Ab, Cbuf);
    k_ln2fc1<<<4096,  256, 0, stream>>>(Cbuf, n2w, n2b, fc1w_bf, fc1b, Dh);
    k_dwconv<<<65536, 256, 0, stream>>>(Dh, dww, dwb, Eh);
    k_cvt   <<<64,    256, 0, stream>>>(fc2w, fc2w_bf, 16384);
    k_fc2   <<<4096,  256, 0, stream>>>(Eh, Cbuf, fc2w_bf, fc2b, out);
}

// Round 3
// 413.465 us; speedup vs baseline: 1.4429x; 1.0328x over previous
//
#include <hip/hip_runtime.h>
#include <hip/hip_bf16.h>
#include <hip/hip_fp8.h>
#include <math.h>

// Problem constants: b=4, c=64, h=w=256, WS=8, SHIFT=4, HEADS=4, d=16, hidden=256
// Windows: 32x32 per image * 4 images = 4096; 64 tokens/window.
//
// Workspace layout (peak 160 MB):
//   Cb  bf16 32MB [0,32M)    x3 token-major        written k2, read k3+k5
//   A   bf16 32MB [32,64M)   shortcut token-major  written k1, read k2 (dead after)
//   Bw  bf16 32MB [64,96M)   shifted windows       written k1, read k2 (dead after)
//   D   fp8  64MB [32,96M)   hid image layout      written k3 (aliases A+Bw), read k4
//   E   fp8  64MB [96,160M)  hid+conv image layout written k4, read k5
//   Wbf bf16 ~66KB at [96M, 96M+66K): prep-converted qkvw/projw/rpb/fc1w,
//       read by k2/k3, then overwritten by k4's E write (safe: stream order).
//   fc2w_bf at [32M): written by k_cvt AFTER k4 (D dead), read k5.

typedef __bf16  bf16x8  __attribute__((ext_vector_type(8)));
typedef float   f32x4   __attribute__((ext_vector_type(4)));
typedef float   f32x2   __attribute__((ext_vector_type(2)));
typedef unsigned short ushortx8 __attribute__((ext_vector_type(8)));

__device__ __forceinline__ float gelu_f(float v) {
    // tanh-form gelu: 0.5v(1+tanh(0.79788456(v+0.044715v^3))) = v - v/(e^u+1)
    // with u = 1.5957691216 v + 0.0713548354 v^3. |err| <~2e-3, << fp8 step.
    float u = v * fmaf(0.0713548354f, v * v, 1.5957691216f);
    float t = __expf(u);                        // t=inf -> rcp=0 -> v;  t=0 -> v-v=0
    float r = __builtin_amdgcn_rcpf(t + 1.0f);
    return v - v * r;
}
__device__ __forceinline__ unsigned char f32_to_fp8(float v) {
    __hip_fp8_e4m3 t(v);
    return (unsigned char)t.__x;
}
__device__ __forceinline__ float fp8_to_f32(unsigned char u) {
    __hip_fp8_e4m3 t;
    t.__x = (__hip_fp8_storage_t)u;
    return (float)t;
}

// Hardware packed fp8 (OCP e4m3 on gfx950) converters; sw fallback if absent.
#if __has_builtin(__builtin_amdgcn_cvt_pk_f32_fp8) && __has_builtin(__builtin_amdgcn_cvt_pk_fp8_f32)
#define HW_FP8 1
#endif
template<bool HI>
__device__ __forceinline__ f32x2 fp8x2_f32(unsigned int u) {
#ifdef HW_FP8
    return __builtin_amdgcn_cvt_pk_f32_fp8((int)u, HI);
#else
    f32x2 r;
    const int s = HI ? 16 : 0;
    r.x = fp8_to_f32((unsigned char)(u >> s));
    r.y = fp8_to_f32((unsigned char)(u >> (s + 8)));
    return r;
#endif
}
template<bool HI>
__device__ __forceinline__ unsigned int f32x2_fp8(float a, float b, unsigned int old) {
#ifdef HW_FP8
    return (unsigned int)__builtin_amdgcn_cvt_pk_fp8_f32(a, b, (int)old, HI);
#else
    unsigned int v = (unsigned int)f32_to_fp8(a) | ((unsigned int)f32_to_fp8(b) << 8);
    return HI ? ((old & 0x0000ffffu) | (v << 16)) : ((old & 0xffff0000u) | v);
#endif
}

__device__ __forceinline__ unsigned short f2bf(float f) {   // RNE, matches HW
    unsigned int u = __builtin_bit_cast(unsigned int, f);
    u += 0x7fffu + ((u >> 16) & 1u);
    return (unsigned short)(u >> 16);
}
__device__ __forceinline__ float bf2f(unsigned short u) {
    return __builtin_bit_cast(float, ((unsigned int)u) << 16);
}

// ---------------------------------------------------------------------------
// Kernel 0: one-time weight conversion to bf16 (amortizes 4096 blocks' worth
// of per-block fp32 loads + f2bf conversions in k2/k3).
// ---------------------------------------------------------------------------
__global__ __launch_bounds__(256) void k_prep(
        const float* __restrict__ qkvw, const float* __restrict__ projw,
        const float* __restrict__ rpb,  const float* __restrict__ fc1w,
        unsigned short* __restrict__ qkvw_bf, unsigned short* __restrict__ projw_bf,
        unsigned short* __restrict__ rpb_bf,  unsigned short* __restrict__ fc1w_bf) {
    const int i = blockIdx.x * 256 + threadIdx.x;   // grid 64*256 = 16384
    if (i < 12288) qkvw_bf[i] = f2bf(qkvw[i]);
    if (i < 4096)  projw_bf[i] = f2bf(projw[i]);
    if (i < 900)   rpb_bf[i]   = f2bf(rpb[i]);
    if (i < 16384) fc1w_bf[i]  = f2bf(fc1w[i]);
}

__global__ __launch_bounds__(256) void k_cvt(const float* __restrict__ src,
        unsigned short* __restrict__ dst, int n) {
    const int i = blockIdx.x * 256 + threadIdx.x;
    if (i < n) dst[i] = f2bf(src[i]);
}

// ---------------------------------------------------------------------------
// Kernel 1: LN1 + transpose. Reads x (b,c,h,w). Writes:
//   A  : shortcut, token-major bf16 [b*65536 tokens][64 ch]
//   Bw : normalized, shifted+window-partitioned bf16 [4096 win][64 tok][64 ch]
// ---------------------------------------------------------------------------
__global__ __launch_bounds__(256) void k_ln1(const float* __restrict__ x,
        const float* __restrict__ w1, const float* __restrict__ b1,
        unsigned short* __restrict__ A, unsigned short* __restrict__ Bw) {
    __shared__ float tile[64 * 65];           // [ch][token]
    __shared__ float red0[256], red1[256];
    __shared__ float muv[64], rsv[64], lw[64], lb[64];
    const int tid = threadIdx.x;
    const int gid = blockIdx.x;
    const int xc = gid & 3, y = (gid >> 2) & 255, b = gid >> 10;
    const int x0 = xc * 64;
    if (tid < 64) { lw[tid] = w1[tid]; lb[tid] = b1[tid]; }

    const float* xb = x + ((size_t)b * 64) * 65536 + y * 256 + x0;
    {
        const int tk = tid & 63, cl = tid >> 6;
        for (int it = 0; it < 16; ++it) {
            int cc = cl + 4 * it;
            tile[cc * 65 + tk] = xb[(size_t)cc * 65536 + tk];   // coalesced
        }
    }
    __syncthreads();
    {
        const int tk = tid & 63, cl = tid >> 6;
        float s = 0.f, s2 = 0.f;
        #pragma unroll
        for (int k = 0; k < 16; ++k) {
            float v = tile[(cl * 16 + k) * 65 + tk];
            s += v; s2 += v * v;
        }
        red0[cl * 64 + tk] = s; red1[cl * 64 + tk] = s2;
    }
    __syncthreads();
    if (tid < 64) {
        float s  = red0[tid] + red0[64 + tid] + red0[128 + tid] + red0[192 + tid];
        float s2 = red1[tid] + red1[64 + tid] + red1[128 + tid] + red1[192 + tid];
        float mu = s * (1.f / 64.f);
        float var = s2 * (1.f / 64.f) - mu * mu;
        muv[tid] = mu; rsv[tid] = rsqrtf(var + 1e-5f);
    }
    __syncthreads();
    const int ch = tid & 63, tl = tid >> 6;
    const int ys = (y + 252) & 255;          // shifted row (roll -4)
    const int wy = ys >> 3, py = ys & 7;
    for (int it = 0; it < 16; ++it) {
        int t = tl + 4 * it;
        float v = tile[ch * 65 + t];         // stride 65 -> free 2-way
        int tok = (b << 16) + y * 256 + x0 + t;
        A[(size_t)tok * 64 + ch] = f2bf(v);
        float vn = (v - muv[t]) * rsv[t] * lw[ch] + lb[ch];
        int xs = (x0 + t + 252) & 255;
        int wx = xs >> 3, px = xs & 7;
        int widx = (b << 10) + (wy << 5) + wx;
        int pos = (py << 3) + px;
        Bw[((size_t)widx * 64 + pos) * 64 + ch] = f2bf(vn);
    }
}

// ---------------------------------------------------------------------------
// Kernel 2: windowed attention, MFMA bf16 (structure as R1: 5 barriers,
// bf16 weights from prep, LDS reuse, edge-window mask skip, unnormalized P).
// ---------------------------------------------------------------------------
__global__ __launch_bounds__(256) void k_attn(
        const unsigned short* __restrict__ Bw,
        const unsigned short* __restrict__ qkvw_bf,
        const unsigned short* __restrict__ projw_bf,
        const unsigned short* __restrict__ rpb_bf,
        const float* __restrict__ qkvb,
        const float* __restrict__ projb,
        const unsigned short* __restrict__ A, unsigned short* __restrict__ Cb) {
    __shared__ __align__(16) unsigned short Xs[4608];    // [64][72] X; later o
    __shared__ __align__(16) unsigned short Ws[13824];   // [192][72] W; then QKV/P/projw
    __shared__ __align__(8)  unsigned short rpbl[900];
    __shared__ float qkvbl[192];
    __shared__ float projbl[64];

    const int tid = threadIdx.x;
    const int lane = tid & 63, wv = tid >> 6;
    const int l15 = lane & 15, quad = lane >> 4;
    const int widx = blockIdx.x;
    const int wib = widx & 1023;
    const int wy = wib >> 5, wx = wib & 31, bimg = widx >> 10;
    const bool edge = (wy == 31) | (wx == 31);   // only these windows have a mask

    const f32x4 zz = {0.f, 0.f, 0.f, 0.f};
    const ushortx8 zu = {0, 0, 0, 0, 0, 0, 0, 0};
    const bf16x8 z8 = __builtin_bit_cast(bf16x8, zu);

    // prefetch projw (2 granules/thread) — consumed after the post-S barrier
    const ushortx8 pw0 = *(const ushortx8*)(projw_bf + tid * 8);
    const ushortx8 pw1 = *(const ushortx8*)(projw_bf + (256 + tid) * 8);

    // stage X: each wave stages its OWN 16 token rows (wave-private)
    {
        const unsigned short* Xg = Bw + (size_t)widx * 4096 + wv * 1024;
        #pragma unroll
        for (int it = 0; it < 2; ++it) {
            int g = it * 64 + lane;                 // granule 0..127
            int row = g >> 3, c8 = g & 7;
            *(ushortx8*)&Xs[(wv * 16 + row) * 72 + c8 * 8] =
                *(const ushortx8*)(Xg + g * 8);
        }
    }
    // stage full qkvw (192 rows, cooperative, b128)
    #pragma unroll
    for (int it = 0; it < 6; ++it) {
        int g = it * 256 + tid;                     // granule 0..1535
        int row = g >> 3, c8 = g & 7;
        *(ushortx8*)&Ws[row * 72 + c8 * 8] = *(const ushortx8*)(qkvw_bf + g * 8);
    }
    if (tid < 225) *(uint2*)&rpbl[tid * 4] = *(const uint2*)(rpb_bf + tid * 4);
    if (tid < 192) qkvbl[tid] = qkvb[tid];
    if (tid < 64)  projbl[tid] = projb[tid];
    __syncthreads();                                // B1

    // QKV: 24 MFMA/thread (A = own 16 token rows of X, B = all 192 W rows)
    f32x4 qacc[12];
    #pragma unroll
    for (int i = 0; i < 12; ++i) qacc[i] = zz;
    {
        const bf16x8 av0 = *(const bf16x8*)&Xs[(16 * wv + l15) * 72 + quad * 8];
        const bf16x8 av1 = *(const bf16x8*)&Xs[(16 * wv + l15) * 72 + 32 + quad * 8];
        #pragma unroll
        for (int gl = 0; gl < 12; ++gl) {
            bf16x8 bv0 = *(const bf16x8*)&Ws[(gl * 16 + l15) * 72 + quad * 8];
            qacc[gl] = __builtin_amdgcn_mfma_f32_16x16x32_bf16(av0, bv0, qacc[gl], 0, 0, 0);
            bf16x8 bv1 = *(const bf16x8*)&Ws[(gl * 16 + l15) * 72 + 32 + quad * 8];
            qacc[gl] = __builtin_amdgcn_mfma_f32_16x16x32_bf16(av1, bv1, qacc[gl], 0, 0, 0);
        }
    }
    __syncthreads();                                // B2 (all W reads done)

    // write Q (scaled) / K / V into Ws
    #pragma unroll
    for (int g = 0; g < 12; ++g) {
        #pragma unroll
        for (int r = 0; r < 4; ++r) {
            int tok = 16 * wv + quad * 4 + r;
            int oc  = g * 16 + l15;
            float v = qacc[g][r] + qkvbl[oc];
            if (g < 4)       Ws[g * 1024 + tok * 16 + l15] = f2bf(v * 0.25f);
            else if (g < 8)  Ws[4096 + (g - 4) * 1024 + tok * 16 + l15] = f2bf(v);
            else             Ws[8192 + ((g - 8) * 16 + l15) * 72 + tok] = f2bf(v);
        }
    }
    __syncthreads();                                // B3

    // S = Q K^T  (16 MFMA/thread)
    f32x4 sacc[4][4];
    #pragma unroll
    for (int h = 0; h < 4; ++h) {
        bf16x8 qa = z8;
        if (quad < 2) qa = *(const bf16x8*)&Ws[h * 1024 + (16 * wv + l15) * 16 + quad * 8];
        #pragma unroll
        for (int nt = 0; nt < 4; ++nt) {
            bf16x8 kf = z8;
            if (quad < 2) kf = *(const bf16x8*)&Ws[4096 + h * 1024 + (nt * 16 + l15) * 16 + quad * 8];
            sacc[h][nt] = __builtin_amdgcn_mfma_f32_16x16x32_bf16(qa, kf, zz, 0, 0, 0);
        }
    }
    __syncthreads();                                // B4 (Q/K reads done)

    // stage projw into the dead K region, XOR-swizzled [oc][64]
    {
        const int r0 = tid >> 3;
        *(ushortx8*)&Ws[4096 + r0 * 64 + (((tid & 7) ^ (r0 & 7)) << 3)] = pw0;
        const int g1 = 256 + tid, r1 = g1 >> 3;
        *(ushortx8*)&Ws[4096 + r1 * 64 + (((g1 & 7) ^ (r1 & 7)) << 3)] = pw1;
    }

    // per-thread j constants
    const int jhi = l15 >> 3, jlo = l15 & 7;
    int offj4[4], regj[4];
    #pragma unroll
    for (int nt = 0; nt < 4; ++nt) {
        int j = nt * 16 + l15;
        int jy = j >> 3, jx = j & 7;
        offj4[nt] = (jy * 15 + jx) * 4;
        regj[nt] = 0;
        if (edge) {
            int ysj = wy * 8 + jy, xsj = wx * 8 + jx;
            regj[nt] = (ysj >= 252 ? 2 : (ysj >= 248 ? 1 : 0)) * 3
                     + (xsj >= 252 ? 2 : (xsj >= 248 ? 1 : 0));
        }
    }
    // per-r constants
    int rbA[4], regiA[4], pbaseA[4], i7A[4];
    #pragma unroll
    for (int r = 0; r < 4; ++r) {
        const int i = 16 * wv + quad * 4 + r;
        const int iy = i >> 3, ix = i & 7;
        rbA[r] = ((iy + 7) * 15 + (ix + 7)) * 4;
        i7A[r] = i & 7;
        pbaseA[r] = i * 64 + jlo;
        regiA[r] = 0;
        if (edge) {
            const int ysi = wy * 8 + iy, xsi = wx * 8 + ix;
            regiA[r] = (ysi >= 252 ? 2 : (ysi >= 248 ? 1 : 0)) * 3
                     + (xsi >= 252 ? 2 : (xsi >= 248 ? 1 : 0));
        }
    }

    // per-head: softmax (P unnormalized into swizzled Q region) + PV
    f32x4 o[4];
    #pragma unroll
    for (int h = 0; h < 4; ++h) {
        float invh[4];
        #pragma unroll
        for (int r = 0; r < 4; ++r) {
            float m0 = -1e30f;
            #pragma unroll
            for (int nt = 0; nt < 4; ++nt) {
                float s = sacc[h][nt][r] + bf2f(rpbl[rbA[r] + h - offj4[nt]]);
                if (edge) s += (regj[nt] == regiA[r]) ? 0.f : -100.f;
                sacc[h][nt][r] = s;
                m0 = fmaxf(m0, s);
            }
            m0 = fmaxf(m0, __shfl_xor(m0, 1));
            m0 = fmaxf(m0, __shfl_xor(m0, 2));
            m0 = fmaxf(m0, __shfl_xor(m0, 4));
            m0 = fmaxf(m0, __shfl_xor(m0, 8));
            float s0 = 0.f;
            #pragma unroll
            for (int nt = 0; nt < 4; ++nt) {
                float e = __expf(sacc[h][nt][r] - m0);
                s0 += e;
                Ws[pbaseA[r] + ((((nt << 1) | jhi) ^ i7A[r]) << 3)] = f2bf(e);
            }
            s0 += __shfl_xor(s0, 1); s0 += __shfl_xor(s0, 2);
            s0 += __shfl_xor(s0, 4); s0 += __shfl_xor(s0, 8);
            invh[r] = 1.f / s0;
        }
        o[h] = zz;
        #pragma unroll
        for (int s = 0; s < 2; ++s) {
            bf16x8 pa = *(const bf16x8*)&Ws[(16 * wv + l15) * 64
                                            + (((s * 4 + quad) ^ (l15 & 7)) << 3)];
            bf16x8 vb = *(const bf16x8*)&Ws[8192 + (h * 16 + l15) * 72 + s * 32 + quad * 8];
            o[h] = __builtin_amdgcn_mfma_f32_16x16x32_bf16(pa, vb, o[h], 0, 0, 0);
        }
        #pragma unroll
        for (int r = 0; r < 4; ++r) o[h][r] *= invh[r];
    }

    // prefetch residual A values (consumed in epilogue; hidden under B5 + proj MFMA)
    unsigned short resid[16];
    #pragma unroll
    for (int r = 0; r < 4; ++r) {
        int tok = 16 * wv + quad * 4 + r;
        int py = tok >> 3, px = tok & 7;
        int yo = (wy * 8 + py + 4) & 255, xo = (wx * 8 + px + 4) & 255;
        size_t gt = ((size_t)bimg << 16) + yo * 256 + xo;
        #pragma unroll
        for (int nt = 0; nt < 4; ++nt)
            resid[r * 4 + nt] = A[gt * 64 + nt * 16 + l15];
    }

    // o -> Xs (own rows only; Xs dead since QKV)
    #pragma unroll
    for (int h = 0; h < 4; ++h)
        #pragma unroll
        for (int r = 0; r < 4; ++r)
            Xs[(16 * wv + quad * 4 + r) * 72 + h * 16 + l15] = f2bf(o[h][r]);
    __syncthreads();                                // B5 (projw + o visible)

    // proj: 8 MFMA/thread
    f32x4 pacc[4];
    #pragma unroll
    for (int nt = 0; nt < 4; ++nt) {
        pacc[nt] = zz;
        #pragma unroll
        for (int s = 0; s < 2; ++s) {
            bf16x8 oa = *(const bf16x8*)&Xs[(16 * wv + l15) * 72 + s * 32 + quad * 8];
            bf16x8 wb = *(const bf16x8*)&Ws[4096 + (nt * 16 + l15) * 64
                                            + (((s * 4 + quad) ^ (l15 & 7)) << 3)];
            pacc[nt] = __builtin_amdgcn_mfma_f32_16x16x32_bf16(oa, wb, pacc[nt], 0, 0, 0);
        }
    }

    // epilogue: bias + residual, un-shift, store Cb
    #pragma unroll
    for (int r = 0; r < 4; ++r) {
        int tok = 16 * wv + quad * 4 + r;
        int py = tok >> 3, px = tok & 7;
        int yo = (wy * 8 + py + 4) & 255, xo = (wx * 8 + px + 4) & 255;
        size_t gt = ((size_t)bimg << 16) + yo * 256 + xo;
        #pragma unroll
        for (int nt = 0; nt < 4; ++nt) {
            int oc = nt * 16 + l15;
            float v = pacc[nt][r] + projbl[oc] + bf2f(resid[r * 4 + nt]);
            Cb[gt * 64 + oc] = f2bf(v);
        }
    }
}

// ---------------------------------------------------------------------------
// Kernel 3: LN2 + fc1 + GELU -> D (image layout fp8), MFMA bf16.
// fc1w staged from prep's bf16 copy (b128); packed HW fp8 store.
// ---------------------------------------------------------------------------
__global__ __launch_bounds__(256) void k_ln2fc1(const unsigned short* __restrict__ Cb,
        const float* __restrict__ w2, const float* __restrict__ b2,
        const unsigned short* __restrict__ fc1w_bf, const float* __restrict__ fc1b,
        unsigned char* __restrict__ D) {
    __shared__ __align__(16) unsigned short Xb[64 * 72];    // raw->normalized bf16
    __shared__ __align__(16) unsigned short Wb[256 * 72];   // fc1w bf16
    __shared__ float red0[256], red1[256];
    __shared__ float muv[64], rsv[64], lwv[64], lbv[64], fb[256];
    const int tid = threadIdx.x, gid = blockIdx.x;
    const int xc = gid & 3, y = (gid >> 2) & 255, b = gid >> 10;
    const int x0 = xc * 64;
    const int lane = tid & 63, wv = tid >> 6;
    const int l15 = lane & 15, quad = lane >> 4;
    const f32x4 zz = {0.f, 0.f, 0.f, 0.f};

    if (tid < 64) { lwv[tid] = w2[tid]; lbv[tid] = b2[tid]; }
    fb[tid] = fc1b[tid];

    // stage Cb -> Xb (raw bf16, coalesced)
    const unsigned short* Cp = Cb + ((size_t)(b << 16) + y * 256 + x0) * 64;
    #pragma unroll
    for (int it = 0; it < 16; ++it) {
        int tt = wv + 4 * it;
        Xb[tt * 72 + lane] = Cp[tt * 64 + lane];
    }
    // stage fc1w_bf -> Wb (b128 copies)
    {
        const ushortx8* w8 = (const ushortx8*)fc1w_bf;
        #pragma unroll
        for (int it = 0; it < 8; ++it) {
            int idx = it * 256 + tid;               // granule 0..2047
            int row = idx >> 3, c8 = idx & 7;
            *(ushortx8*)&Wb[row * 72 + c8 * 8] = w8[idx];
        }
    }
    __syncthreads();
    // LN stats from bf16 tile
    {
        const int tok = tid & 63, cl = tid >> 6;
        float s = 0.f, s2 = 0.f;
        #pragma unroll
        for (int g = 0; g < 2; ++g) {
            const ushortx8 u = *(const ushortx8*)&Xb[tok * 72 + cl * 16 + g * 8];
            #pragma unroll
            for (int k = 0; k < 8; ++k) { float v = bf2f(u[k]); s += v; s2 += v * v; }
        }
        red0[cl * 64 + tok] = s; red1[cl * 64 + tok] = s2;
    }
    __syncthreads();
    if (tid < 64) {
        float s  = red0[tid] + red0[64 + tid] + red0[128 + tid] + red0[192 + tid];
        float s2 = red1[tid] + red1[64 + tid] + red1[128 + tid] + red1[192 + tid];
        float mu = s * (1.f / 64.f);
        float var = s2 * (1.f / 64.f) - mu * mu;
        muv[tid] = mu; rsv[tid] = rsqrtf(var + 1e-5f);
    }
    __syncthreads();
    // normalize in place
    #pragma unroll
    for (int it = 0; it < 16; ++it) {
        int tt = wv + 4 * it;
        float v = bf2f(Xb[tt * 72 + lane]);
        v = (v - muv[tt]) * rsv[tt] * lwv[lane] + lbv[lane];
        Xb[tt * 72 + lane] = f2bf(v);
    }
    __syncthreads();

    // MFMA: acc[mt][nt], m = 64wv+16mt (hidden ch), n = 16nt (token), K=64
    f32x4 acc[4][4];
    #pragma unroll
    for (int mt = 0; mt < 4; ++mt)
        #pragma unroll
        for (int nt = 0; nt < 4; ++nt) acc[mt][nt] = zz;
    #pragma unroll
    for (int s = 0; s < 2; ++s) {
        bf16x8 Bf[4];
        #pragma unroll
        for (int nt = 0; nt < 4; ++nt)
            Bf[nt] = *(const bf16x8*)&Xb[(nt * 16 + l15) * 72 + s * 32 + quad * 8];
        #pragma unroll
        for (int mt = 0; mt < 4; ++mt) {
            bf16x8 Af = *(const bf16x8*)&Wb[(64 * wv + 16 * mt + l15) * 72 + s * 32 + quad * 8];
            #pragma unroll
            for (int nt = 0; nt < 4; ++nt)
                acc[mt][nt] = __builtin_amdgcn_mfma_f32_16x16x32_bf16(Af, Bf[nt], acc[mt][nt], 0, 0, 0);
        }
    }

    // epilogue: bias + gelu + packed fp8 cvt, byte stores (row = hidden ch)
    #pragma unroll
    for (int mt = 0; mt < 4; ++mt) {
        #pragma unroll
        for (int r = 0; r < 4; ++r) {
            const int mch = 64 * wv + 16 * mt + quad * 4 + r;
            const float bias = fb[mch];
            unsigned char* Dp = D + (((size_t)(b * 256 + mch)) << 16) + y * 256 + x0;
            float g0 = gelu_f(acc[mt][0][r] + bias);
            float g1 = gelu_f(acc[mt][1][r] + bias);
            float g2 = gelu_f(acc[mt][2][r] + bias);
            float g3 = gelu_f(acc[mt][3][r] + bias);
            unsigned int pk = f32x2_fp8<false>(g0, g1, 0u);
            pk = f32x2_fp8<true>(g2, g3, pk);
            Dp[l15]      = (unsigned char)(pk);
            Dp[16 + l15] = (unsigned char)(pk >> 8);
            Dp[32 + l15] = (unsigned char)(pk >> 16);
            Dp[48 + l15] = (unsigned char)(pk >> 24);
        }
    }
}

// ---------------------------------------------------------------------------
// Kernel 4: depthwise 5x5 conv + GELU + residual add (image layout, fp8).
// Full-row tiles: 256 wide x 8 tall per block; grid = 1024 (b,ch) x 32 yt.
// Staging: 12 rows x 64 aligned dword units = exactly 3 full 256-thread
// passes (shift/mask indexing, no div, no branches); 2 cvt_pk + 1 aligned
// ds_write_b128 per unit. Each thread computes 2 output rows x 4 cols,
// holding 6 input rows of 8 floats in registers (rows 1..4 shared).
// ---------------------------------------------------------------------------
__global__ __launch_bounds__(256, 4) void k_dwconv(const unsigned char* __restrict__ D,
        const float* __restrict__ dww, const float* __restrict__ dwb,
        unsigned char* __restrict__ E) {
    // sm[r][k]: k -> gx = k - 4 (k=4..259 valid; 0..3 & 260..263 zero pad)
    __shared__ __align__(16) float sm[12 * 264];
    const int tid = threadIdx.x, gid = blockIdx.x;
    const int yt = gid & 31, pc = gid >> 5;
    const int ch = pc & 255;
    const int y0 = yt * 8;
    const unsigned char* Dp = D + ((size_t)pc << 16);

    // halo pad columns (zeros), 24 units
    if (tid < 24) {
        const int r = tid >> 1, side = tid & 1;
        const f32x4 z4 = {0.f, 0.f, 0.f, 0.f};
        *(f32x4*)&sm[r * 264 + side * 260] = z4;
    }
    // interior: 12 rows x 64 dwords = 768 units = 3 full passes
    #pragma unroll
    for (int it = 0; it < 3; ++it) {
        const int u = it * 256 + tid;
        const int r = u >> 6, ci = u & 63;          // gx = 4*ci
        const int gy = y0 + r - 2;
        f32x4 vv = {0.f, 0.f, 0.f, 0.f};
        if ((unsigned)gy < 256u) {
            const unsigned int v = *(const unsigned int*)(Dp + gy * 256 + 4 * ci);
            const f32x2 lo = fp8x2_f32<false>(v);
            const f32x2 hi = fp8x2_f32<true>(v);
            vv.x = lo.x; vv.y = lo.y; vv.z = hi.x; vv.w = hi.y;
        }
        *(f32x4*)&sm[r * 264 + 4 + 4 * ci] = vv;    // 16B aligned
    }
    float wr[25];
    #pragma unroll
    for (int k = 0; k < 25; ++k) wr[k] = dww[ch * 25 + k];   // block-uniform
    const float bb = dwb[ch];
    __syncthreads();

    const int xq = tid & 63, yl = tid >> 6;     // outputs: rows y0+2yl,+1; x=4xq..+3
    float aA0 = bb, aA1 = bb, aA2 = bb, aA3 = bb;
    float aB0 = bb, aB1 = bb, aB2 = bb, aB3 = bb;
    float cA0, cA1, cA2, cA3, cB0, cB1, cB2, cB3;
    // input rows r6 = 0..5 -> LDS row 2*yl + r6; v[i] = sm[row][4xq+2+i]
    #pragma unroll
    for (int r6 = 0; r6 < 6; ++r6) {
        const float* rowp = &sm[(2 * yl + r6) * 264 + 4 * xq + 2];
        f32x2  p0 = *(const f32x2*)rowp;            // 8B aligned
        float4 p1 = *(const float4*)(rowp + 2);     // 16B aligned
        f32x2  p2 = *(const f32x2*)(rowp + 6);      // 8B aligned
        float v[8] = {p0.x, p0.y, p1.x, p1.y, p1.z, p1.w, p2.x, p2.y};
        if (r6 == 2) { cA0 = v[2]; cA1 = v[3]; cA2 = v[4]; cA3 = v[5]; }
        if (r6 == 3) { cB0 = v[2]; cB1 = v[3]; cB2 = v[4]; cB3 = v[5]; }
        if (r6 < 5) {                                // row A, ky = r6
            #pragma unroll
            for (int kx = 0; kx < 5; ++kx) {
                const float w = wr[r6 * 5 + kx];
                aA0 += w * v[kx];     aA1 += w * v[kx + 1];
                aA2 += w * v[kx + 2]; aA3 += w * v[kx + 3];
            }
        }
        if (r6 >= 1) {                               // row B, ky = r6-1
            #pragma unroll
            for (int kx = 0; kx < 5; ++kx) {
                const float w = wr[(r6 - 1) * 5 + kx];
                aB0 += w * v[kx];     aB1 += w * v[kx + 1];
                aB2 += w * v[kx + 2]; aB3 += w * v[kx + 3];
            }
        }
    }
    unsigned int pkA = f32x2_fp8<false>(cA0 + gelu_f(aA0), cA1 + gelu_f(aA1), 0u);
    pkA = f32x2_fp8<true>(cA2 + gelu_f(aA2), cA3 + gelu_f(aA3), pkA);
    unsigned int pkB = f32x2_fp8<false>(cB0 + gelu_f(aB0), cB1 + gelu_f(aB1), 0u);
    pkB = f32x2_fp8<true>(cB2 + gelu_f(aB2), cB3 + gelu_f(aB3), pkB);
    unsigned char* Ep = E + ((size_t)pc << 16) + (y0 + 2 * yl) * 256 + 4 * xq;
    *(unsigned int*)Ep         = pkA;
    *(unsigned int*)(Ep + 256) = pkB;
}

// ---------------------------------------------------------------------------
// Kernel 5: fc2 + bias + residual + transpose -> out (b,c,h,w) fp32, MFMA.
// fc2w staged from k_cvt's bf16 copy; packed HW fp8->f32 on E reads.
// ---------------------------------------------------------------------------
__global__ __launch_bounds__(256) void k_fc2(const unsigned char* __restrict__ E,
        const unsigned short* __restrict__ Cb, const unsigned short* __restrict__ fc2w_bf,
        const float* __restrict__ fc2b, float* __restrict__ out) {
    __shared__ __align__(16) unsigned short Hb[64 * 136];   // [tok][k128 swz]
    __shared__ __align__(16) unsigned short Wb2[64 * 264];  // [oc][k256]
    __shared__ __align__(16) unsigned short Cl[64 * 72];    // residual raw bf16
    __shared__ float fbl[64];
    const int tid = threadIdx.x, gid = blockIdx.x;
    const int xc = gid & 3, y = (gid >> 2) & 255, b = gid >> 10;
    const int x0 = xc * 64;
    const int lane = tid & 63, wv = tid >> 6;
    const int l15 = lane & 15, quad = lane >> 4;
    const f32x4 zz = {0.f, 0.f, 0.f, 0.f};

    if (tid < 64) fbl[tid] = fc2b[tid];
    // stage residual (raw bf16 copy, coalesced)
    {
        const unsigned short* Cp = Cb + ((size_t)(b << 16) + y * 256 + x0) * 64;
        #pragma unroll
        for (int it = 0; it < 16; ++it) {
            int tt = wv + 4 * it;
            Cl[tt * 72 + lane] = Cp[tt * 64 + lane];
        }
    }
    // stage fc2w_bf -> Wb2 (b128 copies)
    {
        const ushortx8* w8 = (const ushortx8*)fc2w_bf;
        #pragma unroll
        for (int it = 0; it < 8; ++it) {
            int idx = it * 256 + tid;               // granule 0..2047
            int row = idx >> 5, c8 = idx & 31;      // 64 rows x 32 granules
            *(ushortx8*)&Wb2[row * 264 + c8 * 8] = w8[idx];
        }
    }

    f32x4 acc[4];
    #pragma unroll
    for (int nt = 0; nt < 4; ++nt) acc[nt] = zz;

    const int ldc = tid >> 4;           // 0..15: channel sub-index for loads
    const int tq  = tid & 15;           // token quad
    unsigned int u0[8];
    // prefetch chunk 0
    #pragma unroll
    for (int it = 0; it < 8; ++it) {
        int chl = ldc + 16 * it;        // 0..127
        u0[it] = *(const unsigned int*)&E[(((size_t)(b * 256 + chl)) << 16) + y * 256 + x0 + 4 * tq];
    }
    __syncthreads();                    // Cl, Wb2 visible

    for (int kc = 0; kc < 2; ++kc) {
        // scatter chunk into Hb with granule swizzle (packed HW cvt)
        #pragma unroll
        for (int it = 0; it < 8; ++it) {
            int chl = ldc + 16 * it;
            f32x2 lo = fp8x2_f32<false>(u0[it]);
            f32x2 hi = fp8x2_f32<true>(u0[it]);
            float vals[4] = {lo.x, lo.y, hi.x, hi.y};
            #pragma unroll
            for (int j = 0; j < 4; ++j) {
                int tok = 4 * tq + j;
                int p = (((chl >> 3) ^ (tok >> 2)) << 3) + (chl & 7);
                Hb[tok * 136 + p] = f2bf(vals[j]);
            }
        }
        // prefetch chunk 1 while chunk 0 computes
        if (kc == 0) {
            #pragma unroll
            for (int it = 0; it < 8; ++it) {
                int chl = ldc + 16 * it + 128;
                u0[it] = *(const unsigned int*)&E[(((size_t)(b * 256 + chl)) << 16) + y * 256 + x0 + 4 * tq];
            }
        }
        __syncthreads();
        // MFMA over this 128-K chunk
        #pragma unroll
        for (int k32 = 0; k32 < 4; ++k32) {
            bf16x8 Af = *(const bf16x8*)&Wb2[(16 * wv + l15) * 264 + kc * 128 + k32 * 32 + quad * 8];
            const int g = k32 * 4 + quad;
            #pragma unroll
            for (int nt = 0; nt < 4; ++nt) {
                const int tok = nt * 16 + l15;
                bf16x8 Bf = *(const bf16x8*)&Hb[tok * 136 + ((g ^ (tok >> 2)) << 3)];
                acc[nt] = __builtin_amdgcn_mfma_f32_16x16x32_bf16(Af, Bf, acc[nt], 0, 0, 0);
            }
        }
        if (kc == 0) __syncthreads();   // before overwriting Hb
    }

    // epilogue: bias + residual, direct fp32 store (row = oc, col = token)
    #pragma unroll
    for (int r = 0; r < 4; ++r) {
        const int oc = 16 * wv + quad * 4 + r;
        const float bias = fbl[oc];
        float* op = out + (((size_t)(b * 64 + oc)) << 16) + y * 256 + x0;
        #pragma unroll
        for (int nt = 0; nt < 4; ++nt) {
            const int tok = nt * 16 + l15;
            op[tok] = acc[nt][r] + bias + bf2f(Cl[tok * 72 + oc]);
        }
    }
}

// ---------------------------------------------------------------------------
extern "C" void kernel_launch(void* const* d_in, const int* in_sizes, int n_in,
                              void* d_out, int out_size, void* d_ws, size_t ws_size,
                              hipStream_t stream) {
    const float* x     = (const float*)d_in[0];
    const float* n1w   = (const float*)d_in[1];
    const float* n1b   = (const float*)d_in[2];
    const float* qkvw  = (const float*)d_in[3];
    const float* qkvb  = (const float*)d_in[4];
    const float* rpb   = (const float*)d_in[5];
    const float* projw = (const float*)d_in[6];
    const float* projb = (const float*)d_in[7];
    const float* n2w   = (const float*)d_in[8];
    const float* n2b   = (const float*)d_in[9];
    const float* fc1w  = (const float*)d_in[10];
    const float* fc1b  = (const float*)d_in[11];
    const float* dww   = (const float*)d_in[12];
    const float* dwb   = (const float*)d_in[13];
    const float* fc2w  = (const float*)d_in[14];
    const float* fc2b  = (const float*)d_in[15];
    float* out = (float*)d_out;

    char* ws = (char*)d_ws;
    const size_t MB = 1048576;
    unsigned short* Cbuf = (unsigned short*)ws;                  // [0,32M)
    unsigned short* Ab   = (unsigned short*)(ws + 32 * MB);      // [32,64M)
    unsigned short* Bwp  = (unsigned short*)(ws + 64 * MB);      // [64,96M)
    unsigned char*  Dh   = (unsigned char*)(ws + 32 * MB);       // [32,96M)  alias A+Bw
    unsigned char*  Eh   = (unsigned char*)(ws + 96 * MB);       // [96,160M)

    // bf16 weight staging areas (inside E region, consumed by k2/k3 BEFORE k4
    // writes E; fc2w_bf in the dead D region, written after k4, read by k5)
    unsigned short* qkvw_bf = (unsigned short*)(ws + 96 * MB);
    unsigned short* projw_bf = (unsigned short*)(ws + 96 * MB + 24576);
    unsigned short* rpb_bf   = (unsigned short*)(ws + 96 * MB + 32768);
    unsigned short* fc1w_bf  = (unsigned short*)(ws + 96 * MB + 34816);
    unsigned short* fc2w_bf  = (unsigned short*)(ws + 32 * MB);

    k_prep  <<<64,    256, 0, stream>>>(qkvw, projw, rpb, fc1w,
                                        qkvw_bf, projw_bf, rpb_bf, fc1w_bf);
    k_ln1   <<<4096,  256, 0, stream>>>(x, n1w, n1b, Ab, Bwp);
    k_attn  <<<4096,  256, 0, stream>>>(Bwp, qkvw_bf, projw_bf, rpb_bf,
                                        qkvb, projb, Ab, Cbuf);
    k_ln2fc1<<<4096,  256, 0, stream>>>(Cbuf, n2w, n2b, fc1w_bf, fc1b, Dh);
    k_dwconv<<<32768, 256, 0, stream>>>(Dh, dww, dwb, Eh);
    k_cvt   <<<64,    256, 0, stream>>>(fc2w, fc2w_bf, 16384);
    k_fc2   <<<4096,  256, 0, stream>>>(Eh, Cbuf, fc2w_bf, fc2b, out);
}

// Round 4
// 389.358 us; speedup vs baseline: 1.5322x; 1.0619x over previous
//
#include <hip/hip_runtime.h>
#include <hip/hip_bf16.h>
#include <hip/hip_fp8.h>
#include <math.h>

// Problem constants: b=4, c=64, h=w=256, WS=8, SHIFT=4, HEADS=4, d=16, hidden=256
// Windows: 32x32 per image * 4 images = 4096; 64 tokens/window.
//
// Workspace layout (peak 160 MB):
//   Cb  bf16 32MB [0,32M)    x3 token-major        written k2, read k3+k5
//   A   bf16 32MB [32,64M)   shortcut token-major  written k1, read k2 (dead after)
//   Bw  bf16 32MB [64,96M)   shifted windows       written k1, read k2 (dead after)
//   D   fp8  64MB [32,96M)   hid image layout      written k3 (aliases A+Bw), read k4
//   E   fp8  64MB [96,160M)  hid+conv image layout written k4, read k5
//   Wbf bf16 ~66KB at [96M, 96M+66K): prep-converted qkvw/projw/rpb/fc1w,
//       read by k2/k3, then overwritten by k4's E write (safe: stream order).
//   fc2w_bf at [32M): written by k_cvt AFTER k4 (D dead), read k5.

typedef __bf16  bf16x8  __attribute__((ext_vector_type(8)));
typedef float   f32x4   __attribute__((ext_vector_type(4)));
typedef float   f32x2   __attribute__((ext_vector_type(2)));
typedef unsigned short ushortx8 __attribute__((ext_vector_type(8)));

__device__ __forceinline__ float gelu_f(float v) {
    // tanh-form gelu: 0.5v(1+tanh(0.79788456(v+0.044715v^3))) = v - v/(e^u+1)
    // with u = 1.5957691216 v + 0.0713548354 v^3. |err| <~2e-3, << fp8 step.
    float u = v * fmaf(0.0713548354f, v * v, 1.5957691216f);
    float t = __expf(u);                        // t=inf -> rcp=0 -> v;  t=0 -> v-v=0
    float r = __builtin_amdgcn_rcpf(t + 1.0f);
    return v - v * r;
}
__device__ __forceinline__ unsigned char f32_to_fp8(float v) {
    __hip_fp8_e4m3 t(v);
    return (unsigned char)t.__x;
}
__device__ __forceinline__ float fp8_to_f32(unsigned char u) {
    __hip_fp8_e4m3 t;
    t.__x = (__hip_fp8_storage_t)u;
    return (float)t;
}

// Hardware packed fp8 (OCP e4m3 on gfx950) converters; sw fallback if absent.
#if __has_builtin(__builtin_amdgcn_cvt_pk_f32_fp8) && __has_builtin(__builtin_amdgcn_cvt_pk_fp8_f32)
#define HW_FP8 1
#endif
template<bool HI>
__device__ __forceinline__ f32x2 fp8x2_f32(unsigned int u) {
#ifdef HW_FP8
    return __builtin_amdgcn_cvt_pk_f32_fp8((int)u, HI);
#else
    f32x2 r;
    const int s = HI ? 16 : 0;
    r.x = fp8_to_f32((unsigned char)(u >> s));
    r.y = fp8_to_f32((unsigned char)(u >> (s + 8)));
    return r;
#endif
}
template<bool HI>
__device__ __forceinline__ unsigned int f32x2_fp8(float a, float b, unsigned int old) {
#ifdef HW_FP8
    return (unsigned int)__builtin_amdgcn_cvt_pk_fp8_f32(a, b, (int)old, HI);
#else
    unsigned int v = (unsigned int)f32_to_fp8(a) | ((unsigned int)f32_to_fp8(b) << 8);
    return HI ? ((old & 0x0000ffffu) | (v << 16)) : ((old & 0xffff0000u) | v);
#endif
}

__device__ __forceinline__ unsigned short f2bf(float f) {   // RNE, matches HW
    unsigned int u = __builtin_bit_cast(unsigned int, f);
    u += 0x7fffu + ((u >> 16) & 1u);
    return (unsigned short)(u >> 16);
}
__device__ __forceinline__ float bf2f(unsigned short u) {
    return __builtin_bit_cast(float, ((unsigned int)u) << 16);
}

// ---------------------------------------------------------------------------
// Kernel 0: one-time weight conversion to bf16 (amortizes 4096 blocks' worth
// of per-block fp32 loads + f2bf conversions in k2/k3).
// ---------------------------------------------------------------------------
__global__ __launch_bounds__(256) void k_prep(
        const float* __restrict__ qkvw, const float* __restrict__ projw,
        const float* __restrict__ rpb,  const float* __restrict__ fc1w,
        unsigned short* __restrict__ qkvw_bf, unsigned short* __restrict__ projw_bf,
        unsigned short* __restrict__ rpb_bf,  unsigned short* __restrict__ fc1w_bf) {
    const int i = blockIdx.x * 256 + threadIdx.x;   // grid 64*256 = 16384
    if (i < 12288) qkvw_bf[i] = f2bf(qkvw[i]);
    if (i < 4096)  projw_bf[i] = f2bf(projw[i]);
    if (i < 900)   rpb_bf[i]   = f2bf(rpb[i]);
    if (i < 16384) fc1w_bf[i]  = f2bf(fc1w[i]);
}

__global__ __launch_bounds__(256) void k_cvt(const float* __restrict__ src,
        unsigned short* __restrict__ dst, int n) {
    const int i = blockIdx.x * 256 + threadIdx.x;
    if (i < n) dst[i] = f2bf(src[i]);
}

// ---------------------------------------------------------------------------
// Kernel 1: LN1 + transpose. Reads x (b,c,h,w). Writes:
//   A  : shortcut, token-major bf16 [b*65536 tokens][64 ch]
//   Bw : normalized, shifted+window-partitioned bf16 [4096 win][64 tok][64 ch]
// ---------------------------------------------------------------------------
__global__ __launch_bounds__(256) void k_ln1(const float* __restrict__ x,
        const float* __restrict__ w1, const float* __restrict__ b1,
        unsigned short* __restrict__ A, unsigned short* __restrict__ Bw) {
    __shared__ float tile[64 * 65];           // [ch][token]
    __shared__ float red0[256], red1[256];
    __shared__ float muv[64], rsv[64], lw[64], lb[64];
    const int tid = threadIdx.x;
    const int gid = blockIdx.x;
    const int xc = gid & 3, y = (gid >> 2) & 255, b = gid >> 10;
    const int x0 = xc * 64;
    if (tid < 64) { lw[tid] = w1[tid]; lb[tid] = b1[tid]; }

    const float* xb = x + ((size_t)b * 64) * 65536 + y * 256 + x0;
    {
        const int tk = tid & 63, cl = tid >> 6;
        for (int it = 0; it < 16; ++it) {
            int cc = cl + 4 * it;
            tile[cc * 65 + tk] = xb[(size_t)cc * 65536 + tk];   // coalesced
        }
    }
    __syncthreads();
    {
        const int tk = tid & 63, cl = tid >> 6;
        float s = 0.f, s2 = 0.f;
        #pragma unroll
        for (int k = 0; k < 16; ++k) {
            float v = tile[(cl * 16 + k) * 65 + tk];
            s += v; s2 += v * v;
        }
        red0[cl * 64 + tk] = s; red1[cl * 64 + tk] = s2;
    }
    __syncthreads();
    if (tid < 64) {
        float s  = red0[tid] + red0[64 + tid] + red0[128 + tid] + red0[192 + tid];
        float s2 = red1[tid] + red1[64 + tid] + red1[128 + tid] + red1[192 + tid];
        float mu = s * (1.f / 64.f);
        float var = s2 * (1.f / 64.f) - mu * mu;
        muv[tid] = mu; rsv[tid] = rsqrtf(var + 1e-5f);
    }
    __syncthreads();
    const int ch = tid & 63, tl = tid >> 6;
    const int ys = (y + 252) & 255;          // shifted row (roll -4)
    const int wy = ys >> 3, py = ys & 7;
    for (int it = 0; it < 16; ++it) {
        int t = tl + 4 * it;
        float v = tile[ch * 65 + t];         // stride 65 -> free 2-way
        int tok = (b << 16) + y * 256 + x0 + t;
        A[(size_t)tok * 64 + ch] = f2bf(v);
        float vn = (v - muv[t]) * rsv[t] * lw[ch] + lb[ch];
        int xs = (x0 + t + 252) & 255;
        int wx = xs >> 3, px = xs & 7;
        int widx = (b << 10) + (wy << 5) + wx;
        int pos = (py << 3) + px;
        Bw[((size_t)widx * 64 + pos) * 64 + ch] = f2bf(vn);
    }
}

// ---------------------------------------------------------------------------
// Kernel 2: windowed attention, MFMA bf16 (structure as R1: 5 barriers,
// bf16 weights from prep, LDS reuse, edge-window mask skip, unnormalized P).
// ---------------------------------------------------------------------------
__global__ __launch_bounds__(256) void k_attn(
        const unsigned short* __restrict__ Bw,
        const unsigned short* __restrict__ qkvw_bf,
        const unsigned short* __restrict__ projw_bf,
        const unsigned short* __restrict__ rpb_bf,
        const float* __restrict__ qkvb,
        const float* __restrict__ projb,
        const unsigned short* __restrict__ A, unsigned short* __restrict__ Cb) {
    __shared__ __align__(16) unsigned short Xs[4608];    // [64][72] X; later o
    __shared__ __align__(16) unsigned short Ws[13824];   // [192][72] W; then QKV/P/projw
    __shared__ __align__(8)  unsigned short rpbl[900];
    __shared__ float qkvbl[192];
    __shared__ float projbl[64];

    const int tid = threadIdx.x;
    const int lane = tid & 63, wv = tid >> 6;
    const int l15 = lane & 15, quad = lane >> 4;
    const int widx = blockIdx.x;
    const int wib = widx & 1023;
    const int wy = wib >> 5, wx = wib & 31, bimg = widx >> 10;
    const bool edge = (wy == 31) | (wx == 31);   // only these windows have a mask

    const f32x4 zz = {0.f, 0.f, 0.f, 0.f};
    const ushortx8 zu = {0, 0, 0, 0, 0, 0, 0, 0};
    const bf16x8 z8 = __builtin_bit_cast(bf16x8, zu);

    // prefetch projw (2 granules/thread) — consumed after the post-S barrier
    const ushortx8 pw0 = *(const ushortx8*)(projw_bf + tid * 8);
    const ushortx8 pw1 = *(const ushortx8*)(projw_bf + (256 + tid) * 8);

    // stage X: each wave stages its OWN 16 token rows (wave-private)
    {
        const unsigned short* Xg = Bw + (size_t)widx * 4096 + wv * 1024;
        #pragma unroll
        for (int it = 0; it < 2; ++it) {
            int g = it * 64 + lane;                 // granule 0..127
            int row = g >> 3, c8 = g & 7;
            *(ushortx8*)&Xs[(wv * 16 + row) * 72 + c8 * 8] =
                *(const ushortx8*)(Xg + g * 8);
        }
    }
    // stage full qkvw (192 rows, cooperative, b128)
    #pragma unroll
    for (int it = 0; it < 6; ++it) {
        int g = it * 256 + tid;                     // granule 0..1535
        int row = g >> 3, c8 = g & 7;
        *(ushortx8*)&Ws[row * 72 + c8 * 8] = *(const ushortx8*)(qkvw_bf + g * 8);
    }
    if (tid < 225) *(uint2*)&rpbl[tid * 4] = *(const uint2*)(rpb_bf + tid * 4);
    if (tid < 192) qkvbl[tid] = qkvb[tid];
    if (tid < 64)  projbl[tid] = projb[tid];
    __syncthreads();                                // B1

    // QKV: 24 MFMA/thread (A = own 16 token rows of X, B = all 192 W rows)
    f32x4 qacc[12];
    #pragma unroll
    for (int i = 0; i < 12; ++i) qacc[i] = zz;
    {
        const bf16x8 av0 = *(const bf16x8*)&Xs[(16 * wv + l15) * 72 + quad * 8];
        const bf16x8 av1 = *(const bf16x8*)&Xs[(16 * wv + l15) * 72 + 32 + quad * 8];
        #pragma unroll
        for (int gl = 0; gl < 12; ++gl) {
            bf16x8 bv0 = *(const bf16x8*)&Ws[(gl * 16 + l15) * 72 + quad * 8];
            qacc[gl] = __builtin_amdgcn_mfma_f32_16x16x32_bf16(av0, bv0, qacc[gl], 0, 0, 0);
            bf16x8 bv1 = *(const bf16x8*)&Ws[(gl * 16 + l15) * 72 + 32 + quad * 8];
            qacc[gl] = __builtin_amdgcn_mfma_f32_16x16x32_bf16(av1, bv1, qacc[gl], 0, 0, 0);
        }
    }
    __syncthreads();                                // B2 (all W reads done)

    // write Q (scaled) / K / V into Ws
    #pragma unroll
    for (int g = 0; g < 12; ++g) {
        #pragma unroll
        for (int r = 0; r < 4; ++r) {
            int tok = 16 * wv + quad * 4 + r;
            int oc  = g * 16 + l15;
            float v = qacc[g][r] + qkvbl[oc];
            if (g < 4)       Ws[g * 1024 + tok * 16 + l15] = f2bf(v * 0.25f);
            else if (g < 8)  Ws[4096 + (g - 4) * 1024 + tok * 16 + l15] = f2bf(v);
            else             Ws[8192 + ((g - 8) * 16 + l15) * 72 + tok] = f2bf(v);
        }
    }
    __syncthreads();                                // B3

    // S = Q K^T  (16 MFMA/thread)
    f32x4 sacc[4][4];
    #pragma unroll
    for (int h = 0; h < 4; ++h) {
        bf16x8 qa = z8;
        if (quad < 2) qa = *(const bf16x8*)&Ws[h * 1024 + (16 * wv + l15) * 16 + quad * 8];
        #pragma unroll
        for (int nt = 0; nt < 4; ++nt) {
            bf16x8 kf = z8;
            if (quad < 2) kf = *(const bf16x8*)&Ws[4096 + h * 1024 + (nt * 16 + l15) * 16 + quad * 8];
            sacc[h][nt] = __builtin_amdgcn_mfma_f32_16x16x32_bf16(qa, kf, zz, 0, 0, 0);
        }
    }
    __syncthreads();                                // B4 (Q/K reads done)

    // stage projw into the dead K region, XOR-swizzled [oc][64]
    {
        const int r0 = tid >> 3;
        *(ushortx8*)&Ws[4096 + r0 * 64 + (((tid & 7) ^ (r0 & 7)) << 3)] = pw0;
        const int g1 = 256 + tid, r1 = g1 >> 3;
        *(ushortx8*)&Ws[4096 + r1 * 64 + (((g1 & 7) ^ (r1 & 7)) << 3)] = pw1;
    }

    // per-thread j constants
    const int jhi = l15 >> 3, jlo = l15 & 7;
    int offj4[4], regj[4];
    #pragma unroll
    for (int nt = 0; nt < 4; ++nt) {
        int j = nt * 16 + l15;
        int jy = j >> 3, jx = j & 7;
        offj4[nt] = (jy * 15 + jx) * 4;
        regj[nt] = 0;
        if (edge) {
            int ysj = wy * 8 + jy, xsj = wx * 8 + jx;
            regj[nt] = (ysj >= 252 ? 2 : (ysj >= 248 ? 1 : 0)) * 3
                     + (xsj >= 252 ? 2 : (xsj >= 248 ? 1 : 0));
        }
    }
    // per-r constants
    int rbA[4], regiA[4], pbaseA[4], i7A[4];
    #pragma unroll
    for (int r = 0; r < 4; ++r) {
        const int i = 16 * wv + quad * 4 + r;
        const int iy = i >> 3, ix = i & 7;
        rbA[r] = ((iy + 7) * 15 + (ix + 7)) * 4;
        i7A[r] = i & 7;
        pbaseA[r] = i * 64 + jlo;
        regiA[r] = 0;
        if (edge) {
            const int ysi = wy * 8 + iy, xsi = wx * 8 + ix;
            regiA[r] = (ysi >= 252 ? 2 : (ysi >= 248 ? 1 : 0)) * 3
                     + (xsi >= 252 ? 2 : (xsi >= 248 ? 1 : 0));
        }
    }

    // per-head: softmax (P unnormalized into swizzled Q region) + PV
    f32x4 o[4];
    #pragma unroll
    for (int h = 0; h < 4; ++h) {
        float invh[4];
        #pragma unroll
        for (int r = 0; r < 4; ++r) {
            float m0 = -1e30f;
            #pragma unroll
            for (int nt = 0; nt < 4; ++nt) {
                float s = sacc[h][nt][r] + bf2f(rpbl[rbA[r] + h - offj4[nt]]);
                if (edge) s += (regj[nt] == regiA[r]) ? 0.f : -100.f;
                sacc[h][nt][r] = s;
                m0 = fmaxf(m0, s);
            }
            m0 = fmaxf(m0, __shfl_xor(m0, 1));
            m0 = fmaxf(m0, __shfl_xor(m0, 2));
            m0 = fmaxf(m0, __shfl_xor(m0, 4));
            m0 = fmaxf(m0, __shfl_xor(m0, 8));
            float s0 = 0.f;
            #pragma unroll
            for (int nt = 0; nt < 4; ++nt) {
                float e = __expf(sacc[h][nt][r] - m0);
                s0 += e;
                Ws[pbaseA[r] + ((((nt << 1) | jhi) ^ i7A[r]) << 3)] = f2bf(e);
            }
            s0 += __shfl_xor(s0, 1); s0 += __shfl_xor(s0, 2);
            s0 += __shfl_xor(s0, 4); s0 += __shfl_xor(s0, 8);
            invh[r] = 1.f / s0;
        }
        o[h] = zz;
        #pragma unroll
        for (int s = 0; s < 2; ++s) {
            bf16x8 pa = *(const bf16x8*)&Ws[(16 * wv + l15) * 64
                                            + (((s * 4 + quad) ^ (l15 & 7)) << 3)];
            bf16x8 vb = *(const bf16x8*)&Ws[8192 + (h * 16 + l15) * 72 + s * 32 + quad * 8];
            o[h] = __builtin_amdgcn_mfma_f32_16x16x32_bf16(pa, vb, o[h], 0, 0, 0);
        }
        #pragma unroll
        for (int r = 0; r < 4; ++r) o[h][r] *= invh[r];
    }

    // prefetch residual A values (consumed in epilogue; hidden under B5 + proj MFMA)
    unsigned short resid[16];
    #pragma unroll
    for (int r = 0; r < 4; ++r) {
        int tok = 16 * wv + quad * 4 + r;
        int py = tok >> 3, px = tok & 7;
        int yo = (wy * 8 + py + 4) & 255, xo = (wx * 8 + px + 4) & 255;
        size_t gt = ((size_t)bimg << 16) + yo * 256 + xo;
        #pragma unroll
        for (int nt = 0; nt < 4; ++nt)
            resid[r * 4 + nt] = A[gt * 64 + nt * 16 + l15];
    }

    // o -> Xs (own rows only; Xs dead since QKV)
    #pragma unroll
    for (int h = 0; h < 4; ++h)
        #pragma unroll
        for (int r = 0; r < 4; ++r)
            Xs[(16 * wv + quad * 4 + r) * 72 + h * 16 + l15] = f2bf(o[h][r]);
    __syncthreads();                                // B5 (projw + o visible)

    // proj: 8 MFMA/thread
    f32x4 pacc[4];
    #pragma unroll
    for (int nt = 0; nt < 4; ++nt) {
        pacc[nt] = zz;
        #pragma unroll
        for (int s = 0; s < 2; ++s) {
            bf16x8 oa = *(const bf16x8*)&Xs[(16 * wv + l15) * 72 + s * 32 + quad * 8];
            bf16x8 wb = *(const bf16x8*)&Ws[4096 + (nt * 16 + l15) * 64
                                            + (((s * 4 + quad) ^ (l15 & 7)) << 3)];
            pacc[nt] = __builtin_amdgcn_mfma_f32_16x16x32_bf16(oa, wb, pacc[nt], 0, 0, 0);
        }
    }

    // epilogue: bias + residual, un-shift, store Cb
    #pragma unroll
    for (int r = 0; r < 4; ++r) {
        int tok = 16 * wv + quad * 4 + r;
        int py = tok >> 3, px = tok & 7;
        int yo = (wy * 8 + py + 4) & 255, xo = (wx * 8 + px + 4) & 255;
        size_t gt = ((size_t)bimg << 16) + yo * 256 + xo;
        #pragma unroll
        for (int nt = 0; nt < 4; ++nt) {
            int oc = nt * 16 + l15;
            float v = pacc[nt][r] + projbl[oc] + bf2f(resid[r * 4 + nt]);
            Cb[gt * 64 + oc] = f2bf(v);
        }
    }
}

// ---------------------------------------------------------------------------
// Kernel 3: LN2 + fc1 + GELU -> D (image layout fp8), MFMA bf16.
// fc1w staged from prep's bf16 copy (b128); packed HW fp8 store.
// ---------------------------------------------------------------------------
__global__ __launch_bounds__(256) void k_ln2fc1(const unsigned short* __restrict__ Cb,
        const float* __restrict__ w2, const float* __restrict__ b2,
        const unsigned short* __restrict__ fc1w_bf, const float* __restrict__ fc1b,
        unsigned char* __restrict__ D) {
    __shared__ __align__(16) unsigned short Xb[64 * 72];    // raw->normalized bf16
    __shared__ __align__(16) unsigned short Wb[256 * 72];   // fc1w bf16
    __shared__ float red0[256], red1[256];
    __shared__ float muv[64], rsv[64], lwv[64], lbv[64], fb[256];
    const int tid = threadIdx.x, gid = blockIdx.x;
    const int xc = gid & 3, y = (gid >> 2) & 255, b = gid >> 10;
    const int x0 = xc * 64;
    const int lane = tid & 63, wv = tid >> 6;
    const int l15 = lane & 15, quad = lane >> 4;
    const f32x4 zz = {0.f, 0.f, 0.f, 0.f};

    if (tid < 64) { lwv[tid] = w2[tid]; lbv[tid] = b2[tid]; }
    fb[tid] = fc1b[tid];

    // stage Cb -> Xb (raw bf16, coalesced)
    const unsigned short* Cp = Cb + ((size_t)(b << 16) + y * 256 + x0) * 64;
    #pragma unroll
    for (int it = 0; it < 16; ++it) {
        int tt = wv + 4 * it;
        Xb[tt * 72 + lane] = Cp[tt * 64 + lane];
    }
    // stage fc1w_bf -> Wb (b128 copies)
    {
        const ushortx8* w8 = (const ushortx8*)fc1w_bf;
        #pragma unroll
        for (int it = 0; it < 8; ++it) {
            int idx = it * 256 + tid;               // granule 0..2047
            int row = idx >> 3, c8 = idx & 7;
            *(ushortx8*)&Wb[row * 72 + c8 * 8] = w8[idx];
        }
    }
    __syncthreads();
    // LN stats from bf16 tile
    {
        const int tok = tid & 63, cl = tid >> 6;
        float s = 0.f, s2 = 0.f;
        #pragma unroll
        for (int g = 0; g < 2; ++g) {
            const ushortx8 u = *(const ushortx8*)&Xb[tok * 72 + cl * 16 + g * 8];
            #pragma unroll
            for (int k = 0; k < 8; ++k) { float v = bf2f(u[k]); s += v; s2 += v * v; }
        }
        red0[cl * 64 + tok] = s; red1[cl * 64 + tok] = s2;
    }
    __syncthreads();
    if (tid < 64) {
        float s  = red0[tid] + red0[64 + tid] + red0[128 + tid] + red0[192 + tid];
        float s2 = red1[tid] + red1[64 + tid] + red1[128 + tid] + red1[192 + tid];
        float mu = s * (1.f / 64.f);
        float var = s2 * (1.f / 64.f) - mu * mu;
        muv[tid] = mu; rsv[tid] = rsqrtf(var + 1e-5f);
    }
    __syncthreads();
    // normalize in place
    #pragma unroll
    for (int it = 0; it < 16; ++it) {
        int tt = wv + 4 * it;
        float v = bf2f(Xb[tt * 72 + lane]);
        v = (v - muv[tt]) * rsv[tt] * lwv[lane] + lbv[lane];
        Xb[tt * 72 + lane] = f2bf(v);
    }
    __syncthreads();

    // MFMA: acc[mt][nt], m = 64wv+16mt (hidden ch), n = 16nt (token), K=64
    f32x4 acc[4][4];
    #pragma unroll
    for (int mt = 0; mt < 4; ++mt)
        #pragma unroll
        for (int nt = 0; nt < 4; ++nt) acc[mt][nt] = zz;
    #pragma unroll
    for (int s = 0; s < 2; ++s) {
        bf16x8 Bf[4];
        #pragma unroll
        for (int nt = 0; nt < 4; ++nt)
            Bf[nt] = *(const bf16x8*)&Xb[(nt * 16 + l15) * 72 + s * 32 + quad * 8];
        #pragma unroll
        for (int mt = 0; mt < 4; ++mt) {
            bf16x8 Af = *(const bf16x8*)&Wb[(64 * wv + 16 * mt + l15) * 72 + s * 32 + quad * 8];
            #pragma unroll
            for (int nt = 0; nt < 4; ++nt)
                acc[mt][nt] = __builtin_amdgcn_mfma_f32_16x16x32_bf16(Af, Bf[nt], acc[mt][nt], 0, 0, 0);
        }
    }

    // epilogue: bias + gelu + packed fp8 cvt, byte stores (row = hidden ch)
    #pragma unroll
    for (int mt = 0; mt < 4; ++mt) {
        #pragma unroll
        for (int r = 0; r < 4; ++r) {
            const int mch = 64 * wv + 16 * mt + quad * 4 + r;
            const float bias = fb[mch];
            unsigned char* Dp = D + (((size_t)(b * 256 + mch)) << 16) + y * 256 + x0;
            float g0 = gelu_f(acc[mt][0][r] + bias);
            float g1 = gelu_f(acc[mt][1][r] + bias);
            float g2 = gelu_f(acc[mt][2][r] + bias);
            float g3 = gelu_f(acc[mt][3][r] + bias);
            unsigned int pk = f32x2_fp8<false>(g0, g1, 0u);
            pk = f32x2_fp8<true>(g2, g3, pk);
            Dp[l15]      = (unsigned char)(pk);
            Dp[16 + l15] = (unsigned char)(pk >> 8);
            Dp[32 + l15] = (unsigned char)(pk >> 16);
            Dp[48 + l15] = (unsigned char)(pk >> 24);
        }
    }
}

// ---------------------------------------------------------------------------
// Kernel 4: depthwise 5x5 conv + GELU + residual via MFMA (banded matmul).
// Block = one (b,ch) x 32 output rows. Input tile staged as bf16 [36][280]
// (left pad 2; stride 280 -> <=2-way LDS banks; fully zero-initialized so
// band-external K garbage is 0, not NaN). A operand = banded weight matrix
// A[i][k] = w[ky][k-i] (zero outside band), built once in LDS. Per 16-px
// x-segment: 5 chained mfma_16x16x32 (one per ky) compute 16px x 16rows.
// Epilogue: out = hid + gelu(conv + bias) -> fp8, staged per-wave in LDS,
// stored coalesced (128B per 4 lanes).
// ---------------------------------------------------------------------------
__global__ __launch_bounds__(256) void k_dwconv(const unsigned char* __restrict__ D,
        const float* __restrict__ dww, const float* __restrict__ dwb,
        unsigned char* __restrict__ E) {
    __shared__ __align__(16) unsigned short inT[36 * 280 + 16]; // [t][2+x], zero-padded
    __shared__ __align__(16) unsigned short Atab[5 * 64 * 8];   // A frags per ky per lane
    __shared__ __align__(16) unsigned char outT[4][16 * 144];   // per-wave [row][px] (pad 144)
    const int tid = threadIdx.x, gid = blockIdx.x;
    const int yt = gid & 7, pc = gid >> 3;        // grid 8192
    const int ch = pc & 255;
    const int y0 = yt * 32;
    const unsigned char* Dp = D + ((size_t)pc << 16);
    const f32x4 zz = {0.f, 0.f, 0.f, 0.f};

    // phase 0: zero-init inT (pads + OOB rows + band-external garbage -> 0.0)
    #pragma unroll
    for (int it = 0; it < 5; ++it) {
        int idx = it * 256 + tid;                 // uint4 units; total 1262
        if (idx < 1262) ((uint4*)inT)[idx] = make_uint4(0, 0, 0, 0);
    }
    __syncthreads();

    // phase 1: stage D (fp8) -> inT (bf16). 36 rows x 64 dwords = 9 passes.
    #pragma unroll
    for (int it = 0; it < 9; ++it) {
        const int u = it * 256 + tid;
        const int t = u >> 6, c = u & 63;
        const int gy = y0 - 2 + t;
        if ((unsigned)gy < 256u) {
            const unsigned int v = *(const unsigned int*)(Dp + gy * 256 + 4 * c);
            const f32x2 lo = fp8x2_f32<false>(v);
            const f32x2 hi = fp8x2_f32<true>(v);
            unsigned int b01 = (unsigned)f2bf(lo.x) | ((unsigned)f2bf(lo.y) << 16);
            unsigned int b23 = (unsigned)f2bf(hi.x) | ((unsigned)f2bf(hi.y) << 16);
            unsigned int* base = (unsigned int*)&inT[t * 280 + 2 + 4 * c];
            base[0] = b01; base[1] = b23;
        }
    }
    // build A-fragment table: entry e=(ky,lane,j): m=lane&15, k=(lane>>4)*8+j
    #pragma unroll
    for (int q = 0; q < 10; ++q) {
        const int e = tid * 10 + q;               // 0..2559
        const int ky = e >> 9, r = e & 511;
        const int l = r >> 3, j = r & 7;
        const int m = l & 15, k = ((l >> 4) << 3) + j;
        const int d = k - m;
        float wv = 0.f;
        if (d >= 0 && d < 5) wv = dww[ch * 25 + ky * 5 + d];
        Atab[e] = f2bf(wv);
    }
    const float bb = dwb[ch];
    __syncthreads();

    // phase 2: MFMA conv
    const int wv_ = tid >> 6, lane = tid & 63;
    const int l15 = lane & 15, quad = lane >> 4;
    const int g = wv_ >> 1, xh = wv_ & 1;         // ygroup(16 rows), xhalf(128 px)
    bf16x8 Af[5];
    #pragma unroll
    for (int ky = 0; ky < 5; ++ky)
        Af[ky] = *(const bf16x8*)&Atab[(ky * 64 + lane) * 8];
    const int tbase = g * 16 + l15;               // B row base (tile row = tbase+ky)

    #pragma unroll
    for (int xp = 0; xp < 8; ++xp) {
        const int xs = xh * 128 + xp * 16;
        f32x4 acc = zz;
        #pragma unroll
        for (int ky = 0; ky < 5; ++ky) {
            // B[k][n]: n=l15 (row), k=quad*8+j -> elems xs+quad*8.. (aligned b128)
            bf16x8 Bf = *(const bf16x8*)&inT[(tbase + ky) * 280 + xs + quad * 8];
            acc = __builtin_amdgcn_mfma_f32_16x16x32_bf16(Af[ky], Bf, acc, 0, 0, 0);
        }
        // epilogue: px X = xs + quad*4 + r (m = quad*4+r), row n = l15
        const unsigned int* cp32 = (const unsigned int*)&inT[(tbase + 2) * 280 + 2 + xs + quad * 4];
        const unsigned int c01 = cp32[0], c23 = cp32[1];
        const float c0 = bf2f((unsigned short)c01), c1 = bf2f((unsigned short)(c01 >> 16));
        const float c2 = bf2f((unsigned short)c23), c3 = bf2f((unsigned short)(c23 >> 16));
        unsigned int pk = f32x2_fp8<false>(c0 + gelu_f(acc[0] + bb), c1 + gelu_f(acc[1] + bb), 0u);
        pk = f32x2_fp8<true>(c2 + gelu_f(acc[2] + bb), c3 + gelu_f(acc[3] + bb), pk);
        *(unsigned int*)&outT[wv_][l15 * 144 + xp * 16 + quad * 4] = pk;
    }

    // phase 3: coalesced store (wave-private outT; compiler inserts lgkmcnt)
    {
        const int row = lane >> 2, sg = lane & 3;
        unsigned char* Ep = E + ((size_t)pc << 16) + (y0 + g * 16 + row) * 256 + xh * 128 + sg * 32;
        *(uint4*)Ep        = *(const uint4*)&outT[wv_][row * 144 + sg * 32];
        *(uint4*)(Ep + 16) = *(const uint4*)&outT[wv_][row * 144 + sg * 32 + 16];
    }
}

// ---------------------------------------------------------------------------
// Kernel 5: fc2 + bias + residual + transpose -> out (b,c,h,w) fp32, MFMA.
// fc2w staged from k_cvt's bf16 copy; packed HW fp8->f32 on E reads.
// ---------------------------------------------------------------------------
__global__ __launch_bounds__(256) void k_fc2(const unsigned char* __restrict__ E,
        const unsigned short* __restrict__ Cb, const unsigned short* __restrict__ fc2w_bf,
        const float* __restrict__ fc2b, float* __restrict__ out) {
    __shared__ __align__(16) unsigned short Hb[64 * 136];   // [tok][k128 swz]
    __shared__ __align__(16) unsigned short Wb2[64 * 264];  // [oc][k256]
    __shared__ __align__(16) unsigned short Cl[64 * 72];    // residual raw bf16
    __shared__ float fbl[64];
    const int tid = threadIdx.x, gid = blockIdx.x;
    const int xc = gid & 3, y = (gid >> 2) & 255, b = gid >> 10;
    const int x0 = xc * 64;
    const int lane = tid & 63, wv = tid >> 6;
    const int l15 = lane & 15, quad = lane >> 4;
    const f32x4 zz = {0.f, 0.f, 0.f, 0.f};

    if (tid < 64) fbl[tid] = fc2b[tid];
    // stage residual (raw bf16 copy, coalesced)
    {
        const unsigned short* Cp = Cb + ((size_t)(b << 16) + y * 256 + x0) * 64;
        #pragma unroll
        for (int it = 0; it < 16; ++it) {
            int tt = wv + 4 * it;
            Cl[tt * 72 + lane] = Cp[tt * 64 + lane];
        }
    }
    // stage fc2w_bf -> Wb2 (b128 copies)
    {
        const ushortx8* w8 = (const ushortx8*)fc2w_bf;
        #pragma unroll
        for (int it = 0; it < 8; ++it) {
            int idx = it * 256 + tid;               // granule 0..2047
            int row = idx >> 5, c8 = idx & 31;      // 64 rows x 32 granules
            *(ushortx8*)&Wb2[row * 264 + c8 * 8] = w8[idx];
        }
    }

    f32x4 acc[4];
    #pragma unroll
    for (int nt = 0; nt < 4; ++nt) acc[nt] = zz;

    const int ldc = tid >> 4;           // 0..15: channel sub-index for loads
    const int tq  = tid & 15;           // token quad
    unsigned int u0[8];
    // prefetch chunk 0
    #pragma unroll
    for (int it = 0; it < 8; ++it) {
        int chl = ldc + 16 * it;        // 0..127
        u0[it] = *(const unsigned int*)&E[(((size_t)(b * 256 + chl)) << 16) + y * 256 + x0 + 4 * tq];
    }
    __syncthreads();                    // Cl, Wb2 visible

    for (int kc = 0; kc < 2; ++kc) {
        // scatter chunk into Hb with granule swizzle (packed HW cvt)
        #pragma unroll
        for (int it = 0; it < 8; ++it) {
            int chl = ldc + 16 * it;
            f32x2 lo = fp8x2_f32<false>(u0[it]);
            f32x2 hi = fp8x2_f32<true>(u0[it]);
            float vals[4] = {lo.x, lo.y, hi.x, hi.y};
            #pragma unroll
            for (int j = 0; j < 4; ++j) {
                int tok = 4 * tq + j;
                int p = (((chl >> 3) ^ (tok >> 2)) << 3) + (chl & 7);
                Hb[tok * 136 + p] = f2bf(vals[j]);
            }
        }
        // prefetch chunk 1 while chunk 0 computes
        if (kc == 0) {
            #pragma unroll
            for (int it = 0; it < 8; ++it) {
                int chl = ldc + 16 * it + 128;
                u0[it] = *(const unsigned int*)&E[(((size_t)(b * 256 + chl)) << 16) + y * 256 + x0 + 4 * tq];
            }
        }
        __syncthreads();
        // MFMA over this 128-K chunk
        #pragma unroll
        for (int k32 = 0; k32 < 4; ++k32) {
            bf16x8 Af = *(const bf16x8*)&Wb2[(16 * wv + l15) * 264 + kc * 128 + k32 * 32 + quad * 8];
            const int g = k32 * 4 + quad;
            #pragma unroll
            for (int nt = 0; nt < 4; ++nt) {
                const int tok = nt * 16 + l15;
                bf16x8 Bf = *(const bf16x8*)&Hb[tok * 136 + ((g ^ (tok >> 2)) << 3)];
                acc[nt] = __builtin_amdgcn_mfma_f32_16x16x32_bf16(Af, Bf, acc[nt], 0, 0, 0);
            }
        }
        if (kc == 0) __syncthreads();   // before overwriting Hb
    }

    // epilogue: bias + residual, direct fp32 store (row = oc, col = token)
    #pragma unroll
    for (int r = 0; r < 4; ++r) {
        const int oc = 16 * wv + quad * 4 + r;
        const float bias = fbl[oc];
        float* op = out + (((size_t)(b * 64 + oc)) << 16) + y * 256 + x0;
        #pragma unroll
        for (int nt = 0; nt < 4; ++nt) {
            const int tok = nt * 16 + l15;
            op[tok] = acc[nt][r] + bias + bf2f(Cl[tok * 72 + oc]);
        }
    }
}

// ---------------------------------------------------------------------------
extern "C" void kernel_launch(void* const* d_in, const int* in_sizes, int n_in,
                              void* d_out, int out_size, void* d_ws, size_t ws_size,
                              hipStream_t stream) {
    const float* x     = (const float*)d_in[0];
    const float* n1w   = (const float*)d_in[1];
    const float* n1b   = (const float*)d_in[2];
    const float* qkvw  = (const float*)d_in[3];
    const float* qkvb  = (const float*)d_in[4];
    const float* rpb   = (const float*)d_in[5];
    const float* projw = (const float*)d_in[6];
    const float* projb = (const float*)d_in[7];
    const float* n2w   = (const float*)d_in[8];
    const float* n2b   = (const float*)d_in[9];
    const float* fc1w  = (const float*)d_in[10];
    const float* fc1b  = (const float*)d_in[11];
    const float* dww   = (const float*)d_in[12];
    const float* dwb   = (const float*)d_in[13];
    const float* fc2w  = (const float*)d_in[14];
    const float* fc2b  = (const float*)d_in[15];
    float* out = (float*)d_out;

    char* ws = (char*)d_ws;
    const size_t MB = 1048576;
    unsigned short* Cbuf = (unsigned short*)ws;                  // [0,32M)
    unsigned short* Ab   = (unsigned short*)(ws + 32 * MB);      // [32,64M)
    unsigned short* Bwp  = (unsigned short*)(ws + 64 * MB);      // [64,96M)
    unsigned char*  Dh   = (unsigned char*)(ws + 32 * MB);       // [32,96M)  alias A+Bw
    unsigned char*  Eh   = (unsigned char*)(ws + 96 * MB);       // [96,160M)

    // bf16 weight staging areas (inside E region, consumed by k2/k3 BEFORE k4
    // writes E; fc2w_bf in the dead D region, written after k4, read by k5)
    unsigned short* qkvw_bf = (unsigned short*)(ws + 96 * MB);
    unsigned short* projw_bf = (unsigned short*)(ws + 96 * MB + 24576);
    unsigned short* rpb_bf   = (unsigned short*)(ws + 96 * MB + 32768);
    unsigned short* fc1w_bf  = (unsigned short*)(ws + 96 * MB + 34816);
    unsigned short* fc2w_bf  = (unsigned short*)(ws + 32 * MB);

    k_prep  <<<64,    256, 0, stream>>>(qkvw, projw, rpb, fc1w,
                                        qkvw_bf, projw_bf, rpb_bf, fc1w_bf);
    k_ln1   <<<4096,  256, 0, stream>>>(x, n1w, n1b, Ab, Bwp);
    k_attn  <<<4096,  256, 0, stream>>>(Bwp, qkvw_bf, projw_bf, rpb_bf,
                                        qkvb, projb, Ab, Cbuf);
    k_ln2fc1<<<4096,  256, 0, stream>>>(Cbuf, n2w, n2b, fc1w_bf, fc1b, Dh);
    k_dwconv<<<8192,  256, 0, stream>>>(Dh, dww, dwb, Eh);
    k_cvt   <<<64,    256, 0, stream>>>(fc2w, fc2w_bf, 16384);
    k_fc2   <<<4096,  256, 0, stream>>>(Eh, Cbuf, fc2w_bf, fc2b, out);
}

// Round 5
// 361.657 us; speedup vs baseline: 1.6496x; 1.0766x over previous
//
#include <hip/hip_runtime.h>
#include <hip/hip_bf16.h>
#include <hip/hip_fp8.h>
#include <math.h>

// Problem constants: b=4, c=64, h=w=256, WS=8, SHIFT=4, HEADS=4, d=16, hidden=256
// Windows: 32x32 per image * 4 images = 4096; 64 tokens/window.
//
// Workspace layout (peak 160 MB):
//   Cb  bf16 32MB [0,32M)    x3 token-major        written k2, read k3+k5
//   A   bf16 32MB [32,64M)   shortcut token-major  written k1, read k2 (dead after)
//   Bw  bf16 32MB [64,96M)   shifted windows       written k1, read k2 (dead after)
//   D   fp8  64MB [32,96M)   hid image layout      written k3 (aliases A+Bw), read k4
//   E   fp8  64MB [96,160M)  hid+conv image layout written k4, read k5
//   Wbf bf16 ~66KB at [96M, 96M+66K): prep-converted qkvw/projw/rpb/fc1w,
//       read by k2/k3, then overwritten by k4's E write (safe: stream order).
//   fc2w_bf at [32M): written by k_cvt AFTER k4 (D dead), read k5.

typedef __bf16  bf16x8  __attribute__((ext_vector_type(8)));
typedef float   f32x4   __attribute__((ext_vector_type(4)));
typedef float   f32x2   __attribute__((ext_vector_type(2)));
typedef unsigned short ushortx8 __attribute__((ext_vector_type(8)));

__device__ __forceinline__ float gelu_f(float v) {
    // tanh-form gelu: 0.5v(1+tanh(0.79788456(v+0.044715v^3))) = v - v/(e^u+1)
    // with u = 1.5957691216 v + 0.0713548354 v^3. |err| <~2e-3, << fp8 step.
    float u = v * fmaf(0.0713548354f, v * v, 1.5957691216f);
    float t = __expf(u);                        // t=inf -> rcp=0 -> v;  t=0 -> v-v=0
    float r = __builtin_amdgcn_rcpf(t + 1.0f);
    return v - v * r;
}
__device__ __forceinline__ unsigned char f32_to_fp8(float v) {
    __hip_fp8_e4m3 t(v);
    return (unsigned char)t.__x;
}
__device__ __forceinline__ float fp8_to_f32(unsigned char u) {
    __hip_fp8_e4m3 t;
    t.__x = (__hip_fp8_storage_t)u;
    return (float)t;
}

// Hardware packed fp8 (OCP e4m3 on gfx950) converters; sw fallback if absent.
#if __has_builtin(__builtin_amdgcn_cvt_pk_f32_fp8) && __has_builtin(__builtin_amdgcn_cvt_pk_fp8_f32)
#define HW_FP8 1
#endif
template<bool HI>
__device__ __forceinline__ f32x2 fp8x2_f32(unsigned int u) {
#ifdef HW_FP8
    return __builtin_amdgcn_cvt_pk_f32_fp8((int)u, HI);
#else
    f32x2 r;
    const int s = HI ? 16 : 0;
    r.x = fp8_to_f32((unsigned char)(u >> s));
    r.y = fp8_to_f32((unsigned char)(u >> (s + 8)));
    return r;
#endif
}
template<bool HI>
__device__ __forceinline__ unsigned int f32x2_fp8(float a, float b, unsigned int old) {
#ifdef HW_FP8
    return (unsigned int)__builtin_amdgcn_cvt_pk_fp8_f32(a, b, (int)old, HI);
#else
    unsigned int v = (unsigned int)f32_to_fp8(a) | ((unsigned int)f32_to_fp8(b) << 8);
    return HI ? ((old & 0x0000ffffu) | (v << 16)) : ((old & 0xffff0000u) | v);
#endif
}

__device__ __forceinline__ unsigned short f2bf(float f) {   // RNE, matches HW
    unsigned int u = __builtin_bit_cast(unsigned int, f);
    u += 0x7fffu + ((u >> 16) & 1u);
    return (unsigned short)(u >> 16);
}
__device__ __forceinline__ float bf2f(unsigned short u) {
    return __builtin_bit_cast(float, ((unsigned int)u) << 16);
}
// packed f32x2 -> 2x bf16 in one dword (lo = a, hi = b); RNE, matches f2bf.
__device__ __forceinline__ unsigned int cvt_pk_bf16(float a, float b) {
#if defined(__gfx950__)
    unsigned int r;
    asm("v_cvt_pk_bf16_f32 %0, %1, %2" : "=v"(r) : "v"(a), "v"(b));
    return r;
#else
    return (unsigned int)f2bf(a) | ((unsigned int)f2bf(b) << 16);
#endif
}

// ---------------------------------------------------------------------------
// Kernel 0: one-time weight conversion to bf16 (amortizes 4096 blocks' worth
// of per-block fp32 loads + f2bf conversions in k2/k3).
// ---------------------------------------------------------------------------
__global__ __launch_bounds__(256) void k_prep(
        const float* __restrict__ qkvw, const float* __restrict__ projw,
        const float* __restrict__ rpb,  const float* __restrict__ fc1w,
        unsigned short* __restrict__ qkvw_bf, unsigned short* __restrict__ projw_bf,
        unsigned short* __restrict__ rpb_bf,  unsigned short* __restrict__ fc1w_bf) {
    const int i = blockIdx.x * 256 + threadIdx.x;   // grid 64*256 = 16384
    if (i < 12288) qkvw_bf[i] = f2bf(qkvw[i]);
    if (i < 4096)  projw_bf[i] = f2bf(projw[i]);
    if (i < 900)   rpb_bf[i]   = f2bf(rpb[i]);
    if (i < 16384) fc1w_bf[i]  = f2bf(fc1w[i]);
}

__global__ __launch_bounds__(256) void k_cvt(const float* __restrict__ src,
        unsigned short* __restrict__ dst, int n) {
    const int i = blockIdx.x * 256 + threadIdx.x;
    if (i < n) dst[i] = f2bf(src[i]);
}

// ---------------------------------------------------------------------------
// Kernel 1: LN1 + transpose. Reads x (b,c,h,w). Writes:
//   A  : shortcut, token-major bf16 [b*65536 tokens][64 ch]
//   Bw : normalized, shifted+window-partitioned bf16 [4096 win][64 tok][64 ch]
// ---------------------------------------------------------------------------
__global__ __launch_bounds__(256) void k_ln1(const float* __restrict__ x,
        const float* __restrict__ w1, const float* __restrict__ b1,
        unsigned short* __restrict__ A, unsigned short* __restrict__ Bw) {
    __shared__ float tile[64 * 65];           // [ch][token]
    __shared__ float red0[256], red1[256];
    __shared__ float muv[64], rsv[64], lw[64], lb[64];
    const int tid = threadIdx.x;
    const int gid = blockIdx.x;
    const int xc = gid & 3, y = (gid >> 2) & 255, b = gid >> 10;
    const int x0 = xc * 64;
    if (tid < 64) { lw[tid] = w1[tid]; lb[tid] = b1[tid]; }

    const float* xb = x + ((size_t)b * 64) * 65536 + y * 256 + x0;
    {
        const int tk = tid & 63, cl = tid >> 6;
        for (int it = 0; it < 16; ++it) {
            int cc = cl + 4 * it;
            tile[cc * 65 + tk] = xb[(size_t)cc * 65536 + tk];   // coalesced
        }
    }
    __syncthreads();
    {
        const int tk = tid & 63, cl = tid >> 6;
        float s = 0.f, s2 = 0.f;
        #pragma unroll
        for (int k = 0; k < 16; ++k) {
            float v = tile[(cl * 16 + k) * 65 + tk];
            s += v; s2 += v * v;
        }
        red0[cl * 64 + tk] = s; red1[cl * 64 + tk] = s2;
    }
    __syncthreads();
    if (tid < 64) {
        float s  = red0[tid] + red0[64 + tid] + red0[128 + tid] + red0[192 + tid];
        float s2 = red1[tid] + red1[64 + tid] + red1[128 + tid] + red1[192 + tid];
        float mu = s * (1.f / 64.f);
        float var = s2 * (1.f / 64.f) - mu * mu;
        muv[tid] = mu; rsv[tid] = rsqrtf(var + 1e-5f);
    }
    __syncthreads();
    const int ch = tid & 63, tl = tid >> 6;
    const int ys = (y + 252) & 255;          // shifted row (roll -4)
    const int wy = ys >> 3, py = ys & 7;
    for (int it = 0; it < 16; ++it) {
        int t = tl + 4 * it;
        float v = tile[ch * 65 + t];         // stride 65 -> free 2-way
        int tok = (b << 16) + y * 256 + x0 + t;
        A[(size_t)tok * 64 + ch] = f2bf(v);
        float vn = (v - muv[t]) * rsv[t] * lw[ch] + lb[ch];
        int xs = (x0 + t + 252) & 255;
        int wx = xs >> 3, px = xs & 7;
        int widx = (b << 10) + (wy << 5) + wx;
        int pos = (py << 3) + px;
        Bw[((size_t)widx * 64 + pos) * 64 + ch] = f2bf(vn);
    }
}

// ---------------------------------------------------------------------------
// Kernel 2: windowed attention, MFMA bf16. R5 softmax restructure:
//  * no max-reduce (scores are O(0.1); exp cannot overflow; shift-invariant)
//  * no sum-reduce: P stored unnormalized; row-sums via extra ones-MFMA in PV
//    (matrix pipe is idle anyway); o scaled by rcp(sum)
//  * bias: one ds_read_b64 per (r,nt) covering all 4 heads (rpb is [idx][4])
//  * P -> bf16 via HW v_cvt_pk_bf16_f32 (1 instr / 2 values)
// ---------------------------------------------------------------------------
__global__ __launch_bounds__(256) void k_attn(
        const unsigned short* __restrict__ Bw,
        const unsigned short* __restrict__ qkvw_bf,
        const unsigned short* __restrict__ projw_bf,
        const unsigned short* __restrict__ rpb_bf,
        const float* __restrict__ qkvb,
        const float* __restrict__ projb,
        const unsigned short* __restrict__ A, unsigned short* __restrict__ Cb) {
    __shared__ __align__(16) unsigned short Xs[4608];    // [64][72] X; later o
    __shared__ __align__(16) unsigned short Ws[13824];   // [192][72] W; then QKV/P/projw
    __shared__ __align__(8)  unsigned short rpbl[900];
    __shared__ float qkvbl[192];
    __shared__ float projbl[64];

    const int tid = threadIdx.x;
    const int lane = tid & 63, wv = tid >> 6;
    const int l15 = lane & 15, quad = lane >> 4;
    const int widx = blockIdx.x;
    const int wib = widx & 1023;
    const int wy = wib >> 5, wx = wib & 31, bimg = widx >> 10;
    const bool edge = (wy == 31) | (wx == 31);   // only these windows have a mask

    const f32x4 zz = {0.f, 0.f, 0.f, 0.f};
    const ushortx8 zu = {0, 0, 0, 0, 0, 0, 0, 0};
    const bf16x8 z8 = __builtin_bit_cast(bf16x8, zu);
    const ushortx8 ou = {0x3F80, 0x3F80, 0x3F80, 0x3F80, 0x3F80, 0x3F80, 0x3F80, 0x3F80};
    const bf16x8 ones8 = __builtin_bit_cast(bf16x8, ou);

    // prefetch projw (2 granules/thread) — consumed after the post-S barrier
    const ushortx8 pw0 = *(const ushortx8*)(projw_bf + tid * 8);
    const ushortx8 pw1 = *(const ushortx8*)(projw_bf + (256 + tid) * 8);

    // stage X: each wave stages its OWN 16 token rows (wave-private)
    {
        const unsigned short* Xg = Bw + (size_t)widx * 4096 + wv * 1024;
        #pragma unroll
        for (int it = 0; it < 2; ++it) {
            int g = it * 64 + lane;                 // granule 0..127
            int row = g >> 3, c8 = g & 7;
            *(ushortx8*)&Xs[(wv * 16 + row) * 72 + c8 * 8] =
                *(const ushortx8*)(Xg + g * 8);
        }
    }
    // stage full qkvw (192 rows, cooperative, b128)
    #pragma unroll
    for (int it = 0; it < 6; ++it) {
        int g = it * 256 + tid;                     // granule 0..1535
        int row = g >> 3, c8 = g & 7;
        *(ushortx8*)&Ws[row * 72 + c8 * 8] = *(const ushortx8*)(qkvw_bf + g * 8);
    }
    if (tid < 225) *(uint2*)&rpbl[tid * 4] = *(const uint2*)(rpb_bf + tid * 4);
    if (tid < 192) qkvbl[tid] = qkvb[tid];
    if (tid < 64)  projbl[tid] = projb[tid];
    __syncthreads();                                // B1

    // QKV: 24 MFMA/thread (A = own 16 token rows of X, B = all 192 W rows)
    f32x4 qacc[12];
    #pragma unroll
    for (int i = 0; i < 12; ++i) qacc[i] = zz;
    {
        const bf16x8 av0 = *(const bf16x8*)&Xs[(16 * wv + l15) * 72 + quad * 8];
        const bf16x8 av1 = *(const bf16x8*)&Xs[(16 * wv + l15) * 72 + 32 + quad * 8];
        #pragma unroll
        for (int gl = 0; gl < 12; ++gl) {
            bf16x8 bv0 = *(const bf16x8*)&Ws[(gl * 16 + l15) * 72 + quad * 8];
            qacc[gl] = __builtin_amdgcn_mfma_f32_16x16x32_bf16(av0, bv0, qacc[gl], 0, 0, 0);
            bf16x8 bv1 = *(const bf16x8*)&Ws[(gl * 16 + l15) * 72 + 32 + quad * 8];
            qacc[gl] = __builtin_amdgcn_mfma_f32_16x16x32_bf16(av1, bv1, qacc[gl], 0, 0, 0);
        }
    }
    __syncthreads();                                // B2 (all W reads done)

    // write Q (scaled) / K / V into Ws
    #pragma unroll
    for (int g = 0; g < 12; ++g) {
        #pragma unroll
        for (int r = 0; r < 4; ++r) {
            int tok = 16 * wv + quad * 4 + r;
            int oc  = g * 16 + l15;
            float v = qacc[g][r] + qkvbl[oc];
            if (g < 4)       Ws[g * 1024 + tok * 16 + l15] = f2bf(v * 0.25f);
            else if (g < 8)  Ws[4096 + (g - 4) * 1024 + tok * 16 + l15] = f2bf(v);
            else             Ws[8192 + ((g - 8) * 16 + l15) * 72 + tok] = f2bf(v);
        }
    }
    __syncthreads();                                // B3

    // S = Q K^T  (16 MFMA/thread)
    f32x4 sacc[4][4];
    #pragma unroll
    for (int h = 0; h < 4; ++h) {
        bf16x8 qa = z8;
        if (quad < 2) qa = *(const bf16x8*)&Ws[h * 1024 + (16 * wv + l15) * 16 + quad * 8];
        #pragma unroll
        for (int nt = 0; nt < 4; ++nt) {
            bf16x8 kf = z8;
            if (quad < 2) kf = *(const bf16x8*)&Ws[4096 + h * 1024 + (nt * 16 + l15) * 16 + quad * 8];
            sacc[h][nt] = __builtin_amdgcn_mfma_f32_16x16x32_bf16(qa, kf, zz, 0, 0, 0);
        }
    }
    __syncthreads();                                // B4 (Q/K reads done)

    // stage projw into the dead K region, XOR-swizzled [oc][64]
    {
        const int r0 = tid >> 3;
        *(ushortx8*)&Ws[4096 + r0 * 64 + (((tid & 7) ^ (r0 & 7)) << 3)] = pw0;
        const int g1 = 256 + tid, r1 = g1 >> 3;
        *(ushortx8*)&Ws[4096 + r1 * 64 + (((g1 & 7) ^ (r1 & 7)) << 3)] = pw1;
    }

    // per-thread j constants
    const int jhi = l15 >> 3, jlo = l15 & 7;
    int offj4[4], regj[4];
    #pragma unroll
    for (int nt = 0; nt < 4; ++nt) {
        int j = nt * 16 + l15;
        int jy = j >> 3, jx = j & 7;
        offj4[nt] = (jy * 15 + jx) * 4;
        regj[nt] = 0;
        if (edge) {
            int ysj = wy * 8 + jy, xsj = wx * 8 + jx;
            regj[nt] = (ysj >= 252 ? 2 : (ysj >= 248 ? 1 : 0)) * 3
                     + (xsj >= 252 ? 2 : (xsj >= 248 ? 1 : 0));
        }
    }
    // per-r constants
    int rbA[4], regiA[4], pbaseA[4], i7A[4];
    #pragma unroll
    for (int r = 0; r < 4; ++r) {
        const int i = 16 * wv + quad * 4 + r;
        const int iy = i >> 3, ix = i & 7;
        rbA[r] = ((iy + 7) * 15 + (ix + 7)) * 4;
        i7A[r] = i & 7;
        pbaseA[r] = i * 64 + jlo;
        regiA[r] = 0;
        if (edge) {
            const int ysi = wy * 8 + iy, xsi = wx * 8 + ix;
            regiA[r] = (ysi >= 252 ? 2 : (ysi >= 248 ? 1 : 0)) * 3
                     + (xsi >= 252 ? 2 : (xsi >= 248 ? 1 : 0));
        }
    }

    // bias + mask pass: one ds_read_b64 per (r,nt) covers all 4 heads
    #pragma unroll
    for (int r = 0; r < 4; ++r) {
        #pragma unroll
        for (int nt = 0; nt < 4; ++nt) {
            const uint2 bw = *(const uint2*)&rpbl[rbA[r] - offj4[nt]];
            float mk = 0.f;
            if (edge) mk = (regj[nt] == regiA[r]) ? 0.f : -100.f;
            sacc[0][nt][r] += __builtin_bit_cast(float, bw.x << 16) + mk;
            sacc[1][nt][r] += __builtin_bit_cast(float, bw.x & 0xffff0000u) + mk;
            sacc[2][nt][r] += __builtin_bit_cast(float, bw.y << 16) + mk;
            sacc[3][nt][r] += __builtin_bit_cast(float, bw.y & 0xffff0000u) + mk;
        }
    }
    // P-store addresses per (r,nt) — shared by all 4 heads
    int pA_[4][4];
    #pragma unroll
    for (int r = 0; r < 4; ++r)
        #pragma unroll
        for (int nt = 0; nt < 4; ++nt)
            pA_[r][nt] = pbaseA[r] + ((((nt << 1) | jhi) ^ i7A[r]) << 3);

    // per-head: exp (no reductions) -> P bf16 (unnormalized) -> PV + ones-MFMA
    f32x4 o[4];
    #pragma unroll
    for (int h = 0; h < 4; ++h) {
        #pragma unroll
        for (int r = 0; r < 4; ++r) {
            const unsigned int pk01 = cvt_pk_bf16(__expf(sacc[h][0][r]),
                                                  __expf(sacc[h][1][r]));
            const unsigned int pk23 = cvt_pk_bf16(__expf(sacc[h][2][r]),
                                                  __expf(sacc[h][3][r]));
            Ws[pA_[r][0]] = (unsigned short)pk01;
            Ws[pA_[r][1]] = (unsigned short)(pk01 >> 16);
            Ws[pA_[r][2]] = (unsigned short)pk23;
            Ws[pA_[r][3]] = (unsigned short)(pk23 >> 16);
        }
        o[h] = zz;
        f32x4 os = zz;
        #pragma unroll
        for (int s = 0; s < 2; ++s) {
            bf16x8 pa = *(const bf16x8*)&Ws[(16 * wv + l15) * 64
                                            + (((s * 4 + quad) ^ (l15 & 7)) << 3)];
            bf16x8 vb = *(const bf16x8*)&Ws[8192 + (h * 16 + l15) * 72 + s * 32 + quad * 8];
            o[h] = __builtin_amdgcn_mfma_f32_16x16x32_bf16(pa, vb, o[h], 0, 0, 0);
            os   = __builtin_amdgcn_mfma_f32_16x16x32_bf16(pa, ones8, os, 0, 0, 0);
        }
        #pragma unroll
        for (int r = 0; r < 4; ++r) o[h][r] *= __builtin_amdgcn_rcpf(os[r]);
    }

    // prefetch residual A values (consumed in epilogue; hidden under B5 + proj MFMA)
    unsigned short resid[16];
    #pragma unroll
    for (int r = 0; r < 4; ++r) {
        int tok = 16 * wv + quad * 4 + r;
        int py = tok >> 3, px = tok & 7;
        int yo = (wy * 8 + py + 4) & 255, xo = (wx * 8 + px + 4) & 255;
        size_t gt = ((size_t)bimg << 16) + yo * 256 + xo;
        #pragma unroll
        for (int nt = 0; nt < 4; ++nt)
            resid[r * 4 + nt] = A[gt * 64 + nt * 16 + l15];
    }

    // o -> Xs (own rows only; Xs dead since QKV)
    #pragma unroll
    for (int h = 0; h < 4; ++h)
        #pragma unroll
        for (int r = 0; r < 4; ++r)
            Xs[(16 * wv + quad * 4 + r) * 72 + h * 16 + l15] = f2bf(o[h][r]);
    __syncthreads();                                // B5 (projw + o visible)

    // proj: 8 MFMA/thread
    f32x4 pacc[4];
    #pragma unroll
    for (int nt = 0; nt < 4; ++nt) {
        pacc[nt] = zz;
        #pragma unroll
        for (int s = 0; s < 2; ++s) {
            bf16x8 oa = *(const bf16x8*)&Xs[(16 * wv + l15) * 72 + s * 32 + quad * 8];
            bf16x8 wb = *(const bf16x8*)&Ws[4096 + (nt * 16 + l15) * 64
                                            + (((s * 4 + quad) ^ (l15 & 7)) << 3)];
            pacc[nt] = __builtin_amdgcn_mfma_f32_16x16x32_bf16(oa, wb, pacc[nt], 0, 0, 0);
        }
    }

    // epilogue: bias + residual, un-shift, store Cb
    #pragma unroll
    for (int r = 0; r < 4; ++r) {
        int tok = 16 * wv + quad * 4 + r;
        int py = tok >> 3, px = tok & 7;
        int yo = (wy * 8 + py + 4) & 255, xo = (wx * 8 + px + 4) & 255;
        size_t gt = ((size_t)bimg << 16) + yo * 256 + xo;
        #pragma unroll
        for (int nt = 0; nt < 4; ++nt) {
            int oc = nt * 16 + l15;
            float v = pacc[nt][r] + projbl[oc] + bf2f(resid[r * 4 + nt]);
            Cb[gt * 64 + oc] = f2bf(v);
        }
    }
}

// ---------------------------------------------------------------------------
// Kernel 3: LN2 + fc1 + GELU -> D (image layout fp8), MFMA bf16.
// fc1w staged from prep's bf16 copy (b128); packed HW fp8 store.
// ---------------------------------------------------------------------------
__global__ __launch_bounds__(256) void k_ln2fc1(const unsigned short* __restrict__ Cb,
        const float* __restrict__ w2, const float* __restrict__ b2,
        const unsigned short* __restrict__ fc1w_bf, const float* __restrict__ fc1b,
        unsigned char* __restrict__ D) {
    __shared__ __align__(16) unsigned short Xb[64 * 72];    // raw->normalized bf16
    __shared__ __align__(16) unsigned short Wb[256 * 72];   // fc1w bf16
    __shared__ float red0[256], red1[256];
    __shared__ float muv[64], rsv[64], lwv[64], lbv[64], fb[256];
    const int tid = threadIdx.x, gid = blockIdx.x;
    const int xc = gid & 3, y = (gid >> 2) & 255, b = gid >> 10;
    const int x0 = xc * 64;
    const int lane = tid & 63, wv = tid >> 6;
    const int l15 = lane & 15, quad = lane >> 4;
    const f32x4 zz = {0.f, 0.f, 0.f, 0.f};

    if (tid < 64) { lwv[tid] = w2[tid]; lbv[tid] = b2[tid]; }
    fb[tid] = fc1b[tid];

    // stage Cb -> Xb (raw bf16, coalesced)
    const unsigned short* Cp = Cb + ((size_t)(b << 16) + y * 256 + x0) * 64;
    #pragma unroll
    for (int it = 0; it < 16; ++it) {
        int tt = wv + 4 * it;
        Xb[tt * 72 + lane] = Cp[tt * 64 + lane];
    }
    // stage fc1w_bf -> Wb (b128 copies)
    {
        const ushortx8* w8 = (const ushortx8*)fc1w_bf;
        #pragma unroll
        for (int it = 0; it < 8; ++it) {
            int idx = it * 256 + tid;               // granule 0..2047
            int row = idx >> 3, c8 = idx & 7;
            *(ushortx8*)&Wb[row * 72 + c8 * 8] = w8[idx];
        }
    }
    __syncthreads();
    // LN stats from bf16 tile
    {
        const int tok = tid & 63, cl = tid >> 6;
        float s = 0.f, s2 = 0.f;
        #pragma unroll
        for (int g = 0; g < 2; ++g) {
            const ushortx8 u = *(const ushortx8*)&Xb[tok * 72 + cl * 16 + g * 8];
            #pragma unroll
            for (int k = 0; k < 8; ++k) { float v = bf2f(u[k]); s += v; s2 += v * v; }
        }
        red0[cl * 64 + tok] = s; red1[cl * 64 + tok] = s2;
    }
    __syncthreads();
    if (tid < 64) {
        float s  = red0[tid] + red0[64 + tid] + red0[128 + tid] + red0[192 + tid];
        float s2 = red1[tid] + red1[64 + tid] + red1[128 + tid] + red1[192 + tid];
        float mu = s * (1.f / 64.f);
        float var = s2 * (1.f / 64.f) - mu * mu;
        muv[tid] = mu; rsv[tid] = rsqrtf(var + 1e-5f);
    }
    __syncthreads();
    // normalize in place
    #pragma unroll
    for (int it = 0; it < 16; ++it) {
        int tt = wv + 4 * it;
        float v = bf2f(Xb[tt * 72 + lane]);
        v = (v - muv[tt]) * rsv[tt] * lwv[lane] + lbv[lane];
        Xb[tt * 72 + lane] = f2bf(v);
    }
    __syncthreads();

    // MFMA: acc[mt][nt], m = 64wv+16mt (hidden ch), n = 16nt (token), K=64
    f32x4 acc[4][4];
    #pragma unroll
    for (int mt = 0; mt < 4; ++mt)
        #pragma unroll
        for (int nt = 0; nt < 4; ++nt) acc[mt][nt] = zz;
    #pragma unroll
    for (int s = 0; s < 2; ++s) {
        bf16x8 Bf[4];
        #pragma unroll
        for (int nt = 0; nt < 4; ++nt)
            Bf[nt] = *(const bf16x8*)&Xb[(nt * 16 + l15) * 72 + s * 32 + quad * 8];
        #pragma unroll
        for (int mt = 0; mt < 4; ++mt) {
            bf16x8 Af = *(const bf16x8*)&Wb[(64 * wv + 16 * mt + l15) * 72 + s * 32 + quad * 8];
            #pragma unroll
            for (int nt = 0; nt < 4; ++nt)
                acc[mt][nt] = __builtin_amdgcn_mfma_f32_16x16x32_bf16(Af, Bf[nt], acc[mt][nt], 0, 0, 0);
        }
    }

    // epilogue: bias + gelu + packed fp8 cvt, byte stores (row = hidden ch)
    #pragma unroll
    for (int mt = 0; mt < 4; ++mt) {
        #pragma unroll
        for (int r = 0; r < 4; ++r) {
            const int mch = 64 * wv + 16 * mt + quad * 4 + r;
            const float bias = fb[mch];
            unsigned char* Dp = D + (((size_t)(b * 256 + mch)) << 16) + y * 256 + x0;
            float g0 = gelu_f(acc[mt][0][r] + bias);
            float g1 = gelu_f(acc[mt][1][r] + bias);
            float g2 = gelu_f(acc[mt][2][r] + bias);
            float g3 = gelu_f(acc[mt][3][r] + bias);
            unsigned int pk = f32x2_fp8<false>(g0, g1, 0u);
            pk = f32x2_fp8<true>(g2, g3, pk);
            Dp[l15]      = (unsigned char)(pk);
            Dp[16 + l15] = (unsigned char)(pk >> 8);
            Dp[32 + l15] = (unsigned char)(pk >> 16);
            Dp[48 + l15] = (unsigned char)(pk >> 24);
        }
    }
}

// ---------------------------------------------------------------------------
// Kernel 4: depthwise 5x5 conv + GELU + residual via MFMA (banded matmul).
// Block = one (b,ch) x 32 output rows. Input tile staged as bf16 [36][280]
// (left pad 2; stride 280 -> <=2-way LDS banks; fully zero-initialized so
// band-external K garbage is 0, not NaN). A operand = banded weight matrix
// A[i][k] = w[ky][k-i] (zero outside band), built once in LDS. Per 16-px
// x-segment: 5 chained mfma_16x16x32 (one per ky) compute 16px x 16rows.
// Epilogue: out = hid + gelu(conv + bias) -> fp8, staged per-wave in LDS,
// stored coalesced (128B per 4 lanes).
// ---------------------------------------------------------------------------
__global__ __launch_bounds__(256) void k_dwconv(const unsigned char* __restrict__ D,
        const float* __restrict__ dww, const float* __restrict__ dwb,
        unsigned char* __restrict__ E) {
    __shared__ __align__(16) unsigned short inT[36 * 280 + 16]; // [t][2+x], zero-padded
    __shared__ __align__(16) unsigned short Atab[5 * 64 * 8];   // A frags per ky per lane
    __shared__ __align__(16) unsigned char outT[4][16 * 144];   // per-wave [row][px] (pad 144)
    const int tid = threadIdx.x, gid = blockIdx.x;
    const int yt = gid & 7, pc = gid >> 3;        // grid 8192
    const int ch = pc & 255;
    const int y0 = yt * 32;
    const unsigned char* Dp = D + ((size_t)pc << 16);
    const f32x4 zz = {0.f, 0.f, 0.f, 0.f};

    // phase 0: zero-init inT (pads + OOB rows + band-external garbage -> 0.0)
    #pragma unroll
    for (int it = 0; it < 5; ++it) {
        int idx = it * 256 + tid;                 // uint4 units; total 1262
        if (idx < 1262) ((uint4*)inT)[idx] = make_uint4(0, 0, 0, 0);
    }
    __syncthreads();

    // phase 1: stage D (fp8) -> inT (bf16). 36 rows x 64 dwords = 9 passes.
    #pragma unroll
    for (int it = 0; it < 9; ++it) {
        const int u = it * 256 + tid;
        const int t = u >> 6, c = u & 63;
        const int gy = y0 - 2 + t;
        if ((unsigned)gy < 256u) {
            const unsigned int v = *(const unsigned int*)(Dp + gy * 256 + 4 * c);
            const f32x2 lo = fp8x2_f32<false>(v);
            const f32x2 hi = fp8x2_f32<true>(v);
            unsigned int b01 = (unsigned)f2bf(lo.x) | ((unsigned)f2bf(lo.y) << 16);
            unsigned int b23 = (unsigned)f2bf(hi.x) | ((unsigned)f2bf(hi.y) << 16);
            unsigned int* base = (unsigned int*)&inT[t * 280 + 2 + 4 * c];
            base[0] = b01; base[1] = b23;
        }
    }
    // build A-fragment table: entry e=(ky,lane,j): m=lane&15, k=(lane>>4)*8+j
    #pragma unroll
    for (int q = 0; q < 10; ++q) {
        const int e = tid * 10 + q;               // 0..2559
        const int ky = e >> 9, r = e & 511;
        const int l = r >> 3, j = r & 7;
        const int m = l & 15, k = ((l >> 4) << 3) + j;
        const int d = k - m;
        float wv = 0.f;
        if (d >= 0 && d < 5) wv = dww[ch * 25 + ky * 5 + d];
        Atab[e] = f2bf(wv);
    }
    const float bb = dwb[ch];
    __syncthreads();

    // phase 2: MFMA conv
    const int wv_ = tid >> 6, lane = tid & 63;
    const int l15 = lane & 15, quad = lane >> 4;
    const int g = wv_ >> 1, xh = wv_ & 1;         // ygroup(16 rows), xhalf(128 px)
    bf16x8 Af[5];
    #pragma unroll
    for (int ky = 0; ky < 5; ++ky)
        Af[ky] = *(const bf16x8*)&Atab[(ky * 64 + lane) * 8];
    const int tbase = g * 16 + l15;               // B row base (tile row = tbase+ky)

    #pragma unroll
    for (int xp = 0; xp < 8; ++xp) {
        const int xs = xh * 128 + xp * 16;
        f32x4 acc = zz;
        #pragma unroll
        for (int ky = 0; ky < 5; ++ky) {
            // B[k][n]: n=l15 (row), k=quad*8+j -> elems xs+quad*8.. (aligned b128)
            bf16x8 Bf = *(const bf16x8*)&inT[(tbase + ky) * 280 + xs + quad * 8];
            acc = __builtin_amdgcn_mfma_f32_16x16x32_bf16(Af[ky], Bf, acc, 0, 0, 0);
        }
        // epilogue: px X = xs + quad*4 + r (m = quad*4+r), row n = l15
        const unsigned int* cp32 = (const unsigned int*)&inT[(tbase + 2) * 280 + 2 + xs + quad * 4];
        const unsigned int c01 = cp32[0], c23 = cp32[1];
        const float c0 = bf2f((unsigned short)c01), c1 = bf2f((unsigned short)(c01 >> 16));
        const float c2 = bf2f((unsigned short)c23), c3 = bf2f((unsigned short)(c23 >> 16));
        unsigned int pk = f32x2_fp8<false>(c0 + gelu_f(acc[0] + bb), c1 + gelu_f(acc[1] + bb), 0u);
        pk = f32x2_fp8<true>(c2 + gelu_f(acc[2] + bb), c3 + gelu_f(acc[3] + bb), pk);
        *(unsigned int*)&outT[wv_][l15 * 144 + xp * 16 + quad * 4] = pk;
    }

    // phase 3: coalesced store (wave-private outT; compiler inserts lgkmcnt)
    {
        const int row = lane >> 2, sg = lane & 3;
        unsigned char* Ep = E + ((size_t)pc << 16) + (y0 + g * 16 + row) * 256 + xh * 128 + sg * 32;
        *(uint4*)Ep        = *(const uint4*)&outT[wv_][row * 144 + sg * 32];
        *(uint4*)(Ep + 16) = *(const uint4*)&outT[wv_][row * 144 + sg * 32 + 16];
    }
}

// ---------------------------------------------------------------------------
// Kernel 5: fc2 + bias + residual + transpose -> out (b,c,h,w) fp32, MFMA.
// fc2w staged from k_cvt's bf16 copy; packed HW fp8->f32 on E reads.
// ---------------------------------------------------------------------------
__global__ __launch_bounds__(256) void k_fc2(const unsigned char* __restrict__ E,
        const unsigned short* __restrict__ Cb, const unsigned short* __restrict__ fc2w_bf,
        const float* __restrict__ fc2b, float* __restrict__ out) {
    __shared__ __align__(16) unsigned short Hb[64 * 136];   // [tok][k128 swz]
    __shared__ __align__(16) unsigned short Wb2[64 * 264];  // [oc][k256]
    __shared__ __align__(16) unsigned short Cl[64 * 72];    // residual raw bf16
    __shared__ float fbl[64];
    const int tid = threadIdx.x, gid = blockIdx.x;
    const int xc = gid & 3, y = (gid >> 2) & 255, b = gid >> 10;
    const int x0 = xc * 64;
    const int lane = tid & 63, wv = tid >> 6;
    const int l15 = lane & 15, quad = lane >> 4;
    const f32x4 zz = {0.f, 0.f, 0.f, 0.f};

    if (tid < 64) fbl[tid] = fc2b[tid];
    // stage residual (raw bf16 copy, coalesced)
    {
        const unsigned short* Cp = Cb + ((size_t)(b << 16) + y * 256 + x0) * 64;
        #pragma unroll
        for (int it = 0; it < 16; ++it) {
            int tt = wv + 4 * it;
            Cl[tt * 72 + lane] = Cp[tt * 64 + lane];
        }
    }
    // stage fc2w_bf -> Wb2 (b128 copies)
    {
        const ushortx8* w8 = (const ushortx8*)fc2w_bf;
        #pragma unroll
        for (int it = 0; it < 8; ++it) {
            int idx = it * 256 + tid;               // granule 0..2047
            int row = idx >> 5, c8 = idx & 31;      // 64 rows x 32 granules
            *(ushortx8*)&Wb2[row * 264 + c8 * 8] = w8[idx];
        }
    }

    f32x4 acc[4];
    #pragma unroll
    for (int nt = 0; nt < 4; ++nt) acc[nt] = zz;

    const int ldc = tid >> 4;           // 0..15: channel sub-index for loads
    const int tq  = tid & 15;           // token quad
    unsigned int u0[8];
    // prefetch chunk 0
    #pragma unroll
    for (int it = 0; it < 8; ++it) {
        int chl = ldc + 16 * it;        // 0..127
        u0[it] = *(const unsigned int*)&E[(((size_t)(b * 256 + chl)) << 16) + y * 256 + x0 + 4 * tq];
    }
    __syncthreads();                    // Cl, Wb2 visible

    for (int kc = 0; kc < 2; ++kc) {
        // scatter chunk into Hb with granule swizzle (packed HW cvt)
        #pragma unroll
        for (int it = 0; it < 8; ++it) {
            int chl = ldc + 16 * it;
            f32x2 lo = fp8x2_f32<false>(u0[it]);
            f32x2 hi = fp8x2_f32<true>(u0[it]);
            float vals[4] = {lo.x, lo.y, hi.x, hi.y};
            #pragma unroll
            for (int j = 0; j < 4; ++j) {
                int tok = 4 * tq + j;
                int p = (((chl >> 3) ^ (tok >> 2)) << 3) + (chl & 7);
                Hb[tok * 136 + p] = f2bf(vals[j]);
            }
        }
        // prefetch chunk 1 while chunk 0 computes
        if (kc == 0) {
            #pragma unroll
            for (int it = 0; it < 8; ++it) {
                int chl = ldc + 16 * it + 128;
                u0[it] = *(const unsigned int*)&E[(((size_t)(b * 256 + chl)) << 16) + y * 256 + x0 + 4 * tq];
            }
        }
        __syncthreads();
        // MFMA over this 128-K chunk
        #pragma unroll
        for (int k32 = 0; k32 < 4; ++k32) {
            bf16x8 Af = *(const bf16x8*)&Wb2[(16 * wv + l15) * 264 + kc * 128 + k32 * 32 + quad * 8];
            const int g = k32 * 4 + quad;
            #pragma unroll
            for (int nt = 0; nt < 4; ++nt) {
                const int tok = nt * 16 + l15;
                bf16x8 Bf = *(const bf16x8*)&Hb[tok * 136 + ((g ^ (tok >> 2)) << 3)];
                acc[nt] = __builtin_amdgcn_mfma_f32_16x16x32_bf16(Af, Bf, acc[nt], 0, 0, 0);
            }
        }
        if (kc == 0) __syncthreads();   // before overwriting Hb
    }

    // epilogue: bias + residual, direct fp32 store (row = oc, col = token)
    #pragma unroll
    for (int r = 0; r < 4; ++r) {
        const int oc = 16 * wv + quad * 4 + r;
        const float bias = fbl[oc];
        float* op = out + (((size_t)(b * 64 + oc)) << 16) + y * 256 + x0;
        #pragma unroll
        for (int nt = 0; nt < 4; ++nt) {
            const int tok = nt * 16 + l15;
            op[tok] = acc[nt][r] + bias + bf2f(Cl[tok * 72 + oc]);
        }
    }
}

// ---------------------------------------------------------------------------
extern "C" void kernel_launch(void* const* d_in, const int* in_sizes, int n_in,
                              void* d_out, int out_size, void* d_ws, size_t ws_size,
                              hipStream_t stream) {
    const float* x     = (const float*)d_in[0];
    const float* n1w   = (const float*)d_in[1];
    const float* n1b   = (const float*)d_in[2];
    const float* qkvw  = (const float*)d_in[3];
    const float* qkvb  = (const float*)d_in[4];
    const float* rpb   = (const float*)d_in[5];
    const float* projw = (const float*)d_in[6];
    const float* projb = (const float*)d_in[7];
    const float* n2w   = (const float*)d_in[8];
    const float* n2b   = (const float*)d_in[9];
    const float* fc1w  = (const float*)d_in[10];
    const float* fc1b  = (const float*)d_in[11];
    const float* dww   = (const float*)d_in[12];
    const float* dwb   = (const float*)d_in[13];
    const float* fc2w  = (const float*)d_in[14];
    const float* fc2b  = (const float*)d_in[15];
    float* out = (float*)d_out;

    char* ws = (char*)d_ws;
    const size_t MB = 1048576;
    unsigned short* Cbuf = (unsigned short*)ws;                  // [0,32M)
    unsigned short* Ab   = (unsigned short*)(ws + 32 * MB);      // [32,64M)
    unsigned short* Bwp  = (unsigned short*)(ws + 64 * MB);      // [64,96M)
    unsigned char*  Dh   = (unsigned char*)(ws + 32 * MB);       // [32,96M)  alias A+Bw
    unsigned char*  Eh   = (unsigned char*)(ws + 96 * MB);       // [96,160M)

    // bf16 weight staging areas (inside E region, consumed by k2/k3 BEFORE k4
    // writes E; fc2w_bf in the dead D region, written after k4, read by k5)
    unsigned short* qkvw_bf = (unsigned short*)(ws + 96 * MB);
    unsigned short* projw_bf = (unsigned short*)(ws + 96 * MB + 24576);
    unsigned short* rpb_bf   = (unsigned short*)(ws + 96 * MB + 32768);
    unsigned short* fc1w_bf  = (unsigned short*)(ws + 96 * MB + 34816);
    unsigned short* fc2w_bf  = (unsigned short*)(ws + 32 * MB);

    k_prep  <<<64,    256, 0, stream>>>(qkvw, projw, rpb, fc1w,
                                        qkvw_bf, projw_bf, rpb_bf, fc1w_bf);
    k_ln1   <<<4096,  256, 0, stream>>>(x, n1w, n1b, Ab, Bwp);
    k_attn  <<<4096,  256, 0, stream>>>(Bwp, qkvw_bf, projw_bf, rpb_bf,
                                        qkvb, projb, Ab, Cbuf);
    k_ln2fc1<<<4096,  256, 0, stream>>>(Cbuf, n2w, n2b, fc1w_bf, fc1b, Dh);
    k_dwconv<<<8192,  256, 0, stream>>>(Dh, dww, dwb, Eh);
    k_cvt   <<<64,    256, 0, stream>>>(fc2w, fc2w_bf, 16384);
    k_fc2   <<<4096,  256, 0, stream>>>(Eh, Cbuf, fc2w_bf, fc2b, out);
}